// Round 2
// baseline (731.107 us; speedup 1.0000x reference)
//
#include <hip/hip_runtime.h>
#include <hip/hip_bf16.h>

// Sizes
#define BATCH 512
#define HID   4096
#define NC    32
#define CD    64
#define CB    1024
#define NCD   2048   // NC*CD

#define WAVE_SYNC() asm volatile("s_waitcnt lgkmcnt(0)" ::: "memory")

// ---------------------------------------------------------------------------
// GEMM (NT): C[m][n] = bias[n] + sum_k A[m][k] * B[n][k]
// A: [M][K] row-major, B: [N][K] row-major. 64x64 tile, 256 thr, 4x4/thread.
// ---------------------------------------------------------------------------
__global__ __launch_bounds__(256) void gemm_nt_bias(
    const float* __restrict__ A, const float* __restrict__ B,
    const float* __restrict__ bias, float* __restrict__ C,
    int M, int N, int K) {
  __shared__ float As[64][68];  // transposed: As[k][m]
  __shared__ float Bs[64][68];  // transposed: Bs[k][n]
  const int t  = threadIdx.x;
  const int tx = t & 15, ty = t >> 4;
  const int bm = blockIdx.x * 64, bn = blockIdx.y * 64;
  const float* Ab = A + (size_t)bm * K;
  const float* Bb = B + (size_t)bn * K;
  float acc[4][4] = {};
  for (int k0 = 0; k0 < K; k0 += 64) {
#pragma unroll
    for (int p = 0; p < 4; ++p) {
      int row = (t >> 4) + p * 16;   // 0..63
      int col = (t & 15) * 4;        // 0..60
      float4 av = *(const float4*)&Ab[(size_t)row * K + k0 + col];
      float4 bv = *(const float4*)&Bb[(size_t)row * K + k0 + col];
      As[col + 0][row] = av.x; As[col + 1][row] = av.y;
      As[col + 2][row] = av.z; As[col + 3][row] = av.w;
      Bs[col + 0][row] = bv.x; Bs[col + 1][row] = bv.y;
      Bs[col + 2][row] = bv.z; Bs[col + 3][row] = bv.w;
    }
    __syncthreads();
#pragma unroll 8
    for (int kk = 0; kk < 64; ++kk) {
      float4 a4 = *(const float4*)&As[kk][ty * 4];
      float4 b4 = *(const float4*)&Bs[kk][tx * 4];
      float a_[4] = {a4.x, a4.y, a4.z, a4.w};
      float b_[4] = {b4.x, b4.y, b4.z, b4.w};
#pragma unroll
      for (int i = 0; i < 4; ++i)
#pragma unroll
        for (int j = 0; j < 4; ++j)
          acc[i][j] += a_[i] * b_[j];
    }
    __syncthreads();
  }
  float4 bv = *(const float4*)&bias[bn + tx * 4];
  float bb[4] = {bv.x, bv.y, bv.z, bv.w};
#pragma unroll
  for (int i = 0; i < 4; ++i) {
    float4 o;
    o.x = acc[i][0] + bb[0];
    o.y = acc[i][1] + bb[1];
    o.z = acc[i][2] + bb[2];
    o.w = acc[i][3] + bb[3];
    *(float4*)&C[(size_t)(bm + ty * 4 + i) * N + bn + tx * 4] = o;
  }
}

// ---------------------------------------------------------------------------
// Per-sample: build 32x1024 cost matrix (Euclidean dist e->codebook) in LDS,
// then wave-0 runs Jonker-Volgenant shortest augmenting path with all
// per-column state (minv, v, used) in REGISTERS (16 cols/lane), argmin via
// shfl_xor butterfly. f64 arithmetic is op-for-op identical to the numpy
// reference, so the assignment is bit-identical.
// One block = one sample. 256 threads. ~156 KiB dynamic LDS.
// ---------------------------------------------------------------------------
#define SMEM_BYTES 156544

__global__ __launch_bounds__(256) void k_assign(
    const float* __restrict__ e_glob, const float* __restrict__ codebook,
    float* __restrict__ q_out, float* __restrict__ idx_out) {
  extern __shared__ char smem_raw[];
  float* cost = (float*)smem_raw;                     // [32][1024] f32
  char* uni = smem_raw + 131072;                      // 25088-byte union
  // fill-phase view
  float* ecache = (float*)uni;                        // [32][64]
  float* cbt    = (float*)(uni + 8192);               // [64][66]
  // hungarian-phase view (overlays ecache after phase B)
  double* u           = (double*)uni;                 // [33]  (264 B)
  unsigned char* pm   = (unsigned char*)(uni + 264);  // [1025]
  unsigned short* way = (unsigned short*)(uni + 1292);// [1025]
  int* idxl           = (int*)(uni + 3344);           // [32]
  // tail
  float* enorm = (float*)(smem_raw + 156160);         // [32]

  const int t = threadIdx.x;
  const int s = blockIdx.x;

  // ---- Phase A: stage e[s] (32x64), compute row norms ----
  {
    const float4* src = (const float4*)(e_glob + (size_t)s * NCD);
    ((float4*)ecache)[t] = src[t];
    ((float4*)ecache)[t + 256] = src[t + 256];
  }
  __syncthreads();
  {
    int r = t >> 3, part = t & 7;
    float sum = 0.f;
#pragma unroll
    for (int i = 0; i < 8; ++i) {
      float e0 = ecache[r * 64 + part * 8 + i];
      sum += e0 * e0;
    }
#pragma unroll
    for (int off = 4; off > 0; off >>= 1) sum += __shfl_down(sum, off);
    if (part == 0) enorm[r] = sum;
  }
  // (visible after the first __syncthreads inside phase B)

  // ---- Phase B: fill cost matrix, 16 tiles of 64 columns ----
  for (int tt = 0; tt < 16; ++tt) {
#pragma unroll
    for (int p = 0; p < 4; ++p) {
      int row = (t >> 4) + p * 16;
      int col = (t & 15) * 4;
      float4 cv = *(const float4*)&codebook[(size_t)(tt * 64 + row) * 64 + col];
      cbt[row * 66 + col + 0] = cv.x; cbt[row * 66 + col + 1] = cv.y;
      cbt[row * 66 + col + 2] = cv.z; cbt[row * 66 + col + 3] = cv.w;
    }
    __syncthreads();
    int jl = t & 31;
    int r0 = (t >> 5) * 4;
    float cn0 = 0.f, cn1 = 0.f;
    float dot[4][2] = {};
    for (int kk = 0; kk < 64; kk += 2) {
      float2 c0 = *(const float2*)&cbt[jl * 66 + kk];
      float2 c1 = *(const float2*)&cbt[(jl + 32) * 66 + kk];
      cn0 += c0.x * c0.x + c0.y * c0.y;
      cn1 += c1.x * c1.x + c1.y * c1.y;
#pragma unroll
      for (int i = 0; i < 4; ++i) {
        float2 ev = *(const float2*)&ecache[(r0 + i) * 64 + kk];
        dot[i][0] += ev.x * c0.x + ev.y * c0.y;
        dot[i][1] += ev.x * c1.x + ev.y * c1.y;
      }
    }
#pragma unroll
    for (int i = 0; i < 4; ++i) {
      float d0 = enorm[r0 + i] + cn0 - 2.f * dot[i][0];
      float d1 = enorm[r0 + i] + cn1 - 2.f * dot[i][1];
      cost[(r0 + i) * 1024 + tt * 64 + jl]      = sqrtf(fmaxf(d0, 0.f));
      cost[(r0 + i) * 1024 + tt * 64 + jl + 32] = sqrtf(fmaxf(d1, 0.f));
    }
    __syncthreads();
  }
  // All 16 tiles done; uni region is free to overlay with hungarian state.

  // ---- Phase C: wave-0 Jonker-Volgenant (registers for minv/v/used) ----
  if (t < 64) {
    const int lane = t;
    for (int j = lane; j < 1025; j += 64) pm[j] = 0;
    if (lane < 33) u[lane] = 0.0;
    double v_[16], minv_[16];
#pragma unroll
    for (int r = 0; r < 16; ++r) v_[r] = 0.0;
    WAVE_SYNC();

    for (int i = 1; i <= NC; ++i) {
#pragma unroll
      for (int r = 0; r < 16; ++r) minv_[r] = 1e300;
      unsigned used_mask = 0;
      if (lane == 0) pm[0] = (unsigned char)i;
      WAVE_SYNC();
      int j0 = 0;
      for (int guard = 0; guard < 1056; ++guard) {
        const int i0 = pm[j0];          // LDS broadcast (same addr all lanes)
        const double ui0 = u[i0];
        double bv = 1e301; int bj = 1 << 20;
#pragma unroll
        for (int r = 0; r < 16; ++r) {
          const int j = 1 + lane + r * 64;
          if (!((used_mask >> r) & 1u)) {
            double cur = (double)cost[(i0 - 1) * 1024 + (j - 1)] - ui0 - v_[r];
            if (cur < minv_[r]) { minv_[r] = cur; way[j] = (unsigned short)j0; }
            if (minv_[r] < bv) { bv = minv_[r]; bj = j; }
          }
        }
        // butterfly all-reduce: (min value, lowest j on ties) -> all lanes
#pragma unroll
        for (int off = 1; off < 64; off <<= 1) {
          double ov = __shfl_xor(bv, off);
          int oj = __shfl_xor(bj, off);
          if (ov < bv || (ov == bv && oj < bj)) { bv = ov; bj = oj; }
        }
        const double delta = bv;
        const int k = bj;
        const int done = (pm[k] == 0);
        // dual update: col 0 (p[0]=i) handled by lane 0; cols 1..1024 by owner
        if (lane == 0) u[i] += delta;
#pragma unroll
        for (int r = 0; r < 16; ++r) {
          const int j = 1 + lane + r * 64;
          if ((used_mask >> r) & 1u) {
            v_[r] -= delta;
            int row = pm[j];            // matched rows are distinct -> no race
            u[row] += delta;
          } else {
            minv_[r] -= delta;
            if (j == k) used_mask |= (1u << r);
          }
        }
        WAVE_SYNC();
        j0 = k;
        if (done) break;
      }
      // augment along the path (way[] entries for path cols were all set)
      WAVE_SYNC();
      if (lane == 0) {
        int jj = j0;
        while (jj != 0) { int j1 = way[jj]; pm[jj] = pm[j1]; jj = j1; }
      }
      WAVE_SYNC();
    }
    // emit indices
    for (int j = 1 + lane; j < 1025; j += 64) {
      int r = pm[j];
      if (r > 0) idxl[r - 1] = j - 1;
    }
  }
  __syncthreads();

  // ---- Phase D: emit indices + gather q ----
  if (t < NC) idx_out[(size_t)s * NC + t] = (float)idxl[t];
  {
    int r = t >> 3, c = (t & 7) * 8;
    int ci = idxl[r];
    float4 q0 = *(const float4*)&codebook[(size_t)ci * 64 + c];
    float4 q1 = *(const float4*)&codebook[(size_t)ci * 64 + c + 4];
    *(float4*)&q_out[(size_t)s * NCD + r * 64 + c]     = q0;
    *(float4*)&q_out[(size_t)s * NCD + r * 64 + c + 4] = q1;
  }
}

// ---------------------------------------------------------------------------
extern "C" void kernel_launch(void* const* d_in, const int* in_sizes, int n_in,
                              void* d_out, int out_size, void* d_ws, size_t ws_size,
                              hipStream_t stream) {
  (void)in_sizes; (void)n_in; (void)out_size; (void)d_ws; (void)ws_size;
  const float* x        = (const float*)d_in[0];
  const float* codebook = (const float*)d_in[1];
  const float* enc_w    = (const float*)d_in[2];
  const float* enc_b    = (const float*)d_in[3];
  const float* dec_w    = (const float*)d_in[4];
  const float* dec_b    = (const float*)d_in[5];

  float* out = (float*)d_out;
  float* r_out   = out;                       // [512][4096]
  float* q_out   = out + 2097152;             // [512][32][64]
  float* e_out   = out + 2097152 + 1048576;   // [512][32][64]
  float* idx_out = out + 2097152 + 2097152;   // [512][32] as float

  // K1: e = x @ enc_w.T + enc_b   (M=512, N=2048, K=4096)
  gemm_nt_bias<<<dim3(BATCH / 64, NCD / 64), 256, 0, stream>>>(
      x, enc_w, enc_b, e_out, BATCH, NCD, HID);

  // K2: distances + Hungarian + q gather (one block per sample)
  (void)hipFuncSetAttribute((const void*)k_assign,
                            hipFuncAttributeMaxDynamicSharedMemorySize,
                            SMEM_BYTES);
  k_assign<<<BATCH, 256, SMEM_BYTES, stream>>>(e_out, codebook, q_out, idx_out);

  // K3: r = q @ dec_w.T + dec_b   (M=512, N=4096, K=2048)
  gemm_nt_bias<<<dim3(BATCH / 64, HID / 64), 256, 0, stream>>>(
      q_out, dec_w, dec_b, r_out, BATCH, HID, NCD);
}

// Round 3
// 636.397 us; speedup vs baseline: 1.1488x; 1.1488x over previous
//
#include <hip/hip_runtime.h>
#include <hip/hip_bf16.h>

// Sizes
#define BATCH 512
#define HID   4096
#define NC    32
#define CD    64
#define CB    1024
#define NCD   2048   // NC*CD

#define WAVE_SYNC()  asm volatile("s_waitcnt lgkmcnt(0)" ::: "memory")
#define SCHED_FENCE() __builtin_amdgcn_sched_barrier(0)

// ---------------------------------------------------------------------------
// GEMM (NT): C[m][n] = bias[n] + sum_k A[m][k] * B[n][k]
// A: [M][K] row-major, B: [N][K] row-major. 64x64 tile, 256 thr, 4x4/thread.
// ---------------------------------------------------------------------------
__global__ __launch_bounds__(256) void gemm_nt_bias(
    const float* __restrict__ A, const float* __restrict__ B,
    const float* __restrict__ bias, float* __restrict__ C,
    int M, int N, int K) {
  __shared__ float As[64][68];  // transposed: As[k][m]
  __shared__ float Bs[64][68];  // transposed: Bs[k][n]
  const int t  = threadIdx.x;
  const int tx = t & 15, ty = t >> 4;
  const int bm = blockIdx.x * 64, bn = blockIdx.y * 64;
  const float* Ab = A + (size_t)bm * K;
  const float* Bb = B + (size_t)bn * K;
  float acc[4][4] = {};
  for (int k0 = 0; k0 < K; k0 += 64) {
#pragma unroll
    for (int p = 0; p < 4; ++p) {
      int row = (t >> 4) + p * 16;   // 0..63
      int col = (t & 15) * 4;        // 0..60
      float4 av = *(const float4*)&Ab[(size_t)row * K + k0 + col];
      float4 bv = *(const float4*)&Bb[(size_t)row * K + k0 + col];
      As[col + 0][row] = av.x; As[col + 1][row] = av.y;
      As[col + 2][row] = av.z; As[col + 3][row] = av.w;
      Bs[col + 0][row] = bv.x; Bs[col + 1][row] = bv.y;
      Bs[col + 2][row] = bv.z; Bs[col + 3][row] = bv.w;
    }
    __syncthreads();
#pragma unroll 8
    for (int kk = 0; kk < 64; ++kk) {
      float4 a4 = *(const float4*)&As[kk][ty * 4];
      float4 b4 = *(const float4*)&Bs[kk][tx * 4];
      float a_[4] = {a4.x, a4.y, a4.z, a4.w};
      float b_[4] = {b4.x, b4.y, b4.z, b4.w};
#pragma unroll
      for (int i = 0; i < 4; ++i)
#pragma unroll
        for (int j = 0; j < 4; ++j)
          acc[i][j] += a_[i] * b_[j];
    }
    __syncthreads();
  }
  float4 bv = *(const float4*)&bias[bn + tx * 4];
  float bb[4] = {bv.x, bv.y, bv.z, bv.w};
#pragma unroll
  for (int i = 0; i < 4; ++i) {
    float4 o;
    o.x = acc[i][0] + bb[0];
    o.y = acc[i][1] + bb[1];
    o.z = acc[i][2] + bb[2];
    o.w = acc[i][3] + bb[3];
    *(float4*)&C[(size_t)(bm + ty * 4 + i) * N + bn + tx * 4] = o;
  }
}

// ---------------------------------------------------------------------------
// k_cost: cost[r][c] = || e[r] - codebook[c] ||, r in [0,16384), c in [0,1024).
// Block: 64 e-rows x 256 cols (4 subtiles of 64). Grid (256, 4). 256 threads.
// Operands staged transposed ([k][row]) so the inner loop is two broadcast
// b128 reads + 16 fma per k. ~36 KiB LDS -> 4 blocks/CU.
// ---------------------------------------------------------------------------
__global__ __launch_bounds__(256) void k_cost(
    const float* __restrict__ e_glob,     // [16384][64]
    const float* __restrict__ codebook,   // [1024][64]
    float* __restrict__ cost) {           // [16384][1024]
  __shared__ float es[64][68];   // es[k][row]
  __shared__ float cs[64][68];   // cs[k][col], re-staged per subtile
  __shared__ float enorm[64], cnorm[64];
  const int t = threadIdx.x;
  const int r0 = blockIdx.x * 64;
  const int c0 = blockIdx.y * 256;
  const int tx = t & 15, ty = t >> 4;

  // stage e-tile transposed (wave-uniform k-quarter, lane = row)
  {
    int row = t & 63, kq = t >> 6;
    const float* src = e_glob + (size_t)(r0 + row) * 64 + kq * 16;
#pragma unroll
    for (int i = 0; i < 4; ++i) {
      float4 v = *(const float4*)(src + i * 4);
      int kk = kq * 16 + i * 4;
      es[kk + 0][row] = v.x; es[kk + 1][row] = v.y;
      es[kk + 2][row] = v.z; es[kk + 3][row] = v.w;
    }
  }
  __syncthreads();
  if (t < 64) {
    float s = 0.f;
    for (int kk = 0; kk < 64; ++kk) { float x = es[kk][t]; s = fmaf(x, x, s); }
    enorm[t] = s;
  }

  for (int sub = 0; sub < 4; ++sub) {
    __syncthreads();   // prior compute (or enorm) done before re-staging cs
    {
      int col = t & 63, kq = t >> 6;
      const float* src = codebook + (size_t)(c0 + sub * 64 + col) * 64 + kq * 16;
#pragma unroll
      for (int i = 0; i < 4; ++i) {
        float4 v = *(const float4*)(src + i * 4);
        int kk = kq * 16 + i * 4;
        cs[kk + 0][col] = v.x; cs[kk + 1][col] = v.y;
        cs[kk + 2][col] = v.z; cs[kk + 3][col] = v.w;
      }
    }
    __syncthreads();
    if (t < 64) {
      float s = 0.f;
      for (int kk = 0; kk < 64; ++kk) { float x = cs[kk][t]; s = fmaf(x, x, s); }
      cnorm[t] = s;
    }
    __syncthreads();

    float dot[4][4] = {};
#pragma unroll 8
    for (int kk = 0; kk < 64; ++kk) {
      float4 a4 = *(const float4*)&es[kk][ty * 4];
      float4 b4 = *(const float4*)&cs[kk][tx * 4];
      float a_[4] = {a4.x, a4.y, a4.z, a4.w};
      float b_[4] = {b4.x, b4.y, b4.z, b4.w};
#pragma unroll
      for (int i = 0; i < 4; ++i)
#pragma unroll
        for (int j = 0; j < 4; ++j)
          dot[i][j] = fmaf(a_[i], b_[j], dot[i][j]);
    }
#pragma unroll
    for (int i = 0; i < 4; ++i) {
      int r = ty * 4 + i;
      float en = enorm[r];
      float4 o;
      o.x = sqrtf(fmaxf(en + cnorm[tx * 4 + 0] - 2.f * dot[i][0], 0.f));
      o.y = sqrtf(fmaxf(en + cnorm[tx * 4 + 1] - 2.f * dot[i][1], 0.f));
      o.z = sqrtf(fmaxf(en + cnorm[tx * 4 + 2] - 2.f * dot[i][2], 0.f));
      o.w = sqrtf(fmaxf(en + cnorm[tx * 4 + 3] - 2.f * dot[i][3], 0.f));
      *(float4*)&cost[(size_t)(r0 + r) * CB + c0 + sub * 64 + tx * 4] = o;
    }
  }
}

// ---------------------------------------------------------------------------
// k_assign: one wave per sample. Jonker-Volgenant with per-column state in
// registers (16 cols/lane), argmin via shfl_xor butterfly, cost rows read
// from global (L2/L3-resident). Tiny LDS -> high occupancy, all 512 samples
// solved concurrently. f64 math op-for-op identical to the numpy reference.
// ---------------------------------------------------------------------------
__global__ __launch_bounds__(64) void k_assign(
    const float* __restrict__ cost_g, const float* __restrict__ codebook,
    float* __restrict__ q_out, float* __restrict__ idx_out) {
  __shared__ double u[33];
  __shared__ unsigned short way[1025];
  __shared__ unsigned char pm[1025];
  __shared__ int idxl[32];
  const int lane = threadIdx.x;
  const int s = blockIdx.x;
  const float* __restrict__ cost = cost_g + (size_t)s * NC * CB;

  for (int j = lane; j < 1025; j += 64) pm[j] = 0;
  if (lane < 33) u[lane] = 0.0;
  double v_[16], minv_[16];
#pragma unroll
  for (int r = 0; r < 16; ++r) v_[r] = 0.0;
  WAVE_SYNC(); SCHED_FENCE();

  for (int i = 1; i <= NC; ++i) {
#pragma unroll
    for (int r = 0; r < 16; ++r) minv_[r] = 1e300;
    unsigned used_mask = 0;
    if (lane == 0) pm[0] = (unsigned char)i;
    WAVE_SYNC(); SCHED_FENCE();
    int j0 = 0;
    for (int guard = 0; guard < 1056; ++guard) {
      const int i0 = pm[j0];          // LDS broadcast
      const double ui0 = u[i0];
      const float* crow = cost + (size_t)(i0 - 1) * CB - 1;  // 1-based j
      double bv = 1e301; int bj = 1 << 20;
#pragma unroll
      for (int r = 0; r < 16; ++r) {
        const int j = 1 + lane + r * 64;
        if (!((used_mask >> r) & 1u)) {
          double cur = (double)crow[j] - ui0 - v_[r];
          if (cur < minv_[r]) { minv_[r] = cur; way[j] = (unsigned short)j0; }
          if (minv_[r] < bv) { bv = minv_[r]; bj = j; }
        }
      }
      // butterfly all-reduce: (min value, lowest j on ties) -> all lanes
#pragma unroll
      for (int off = 1; off < 64; off <<= 1) {
        double ov = __shfl_xor(bv, off);
        int oj = __shfl_xor(bj, off);
        if (ov < bv || (ov == bv && oj < bj)) { bv = ov; bj = oj; }
      }
      const double delta = bv;
      const int k = bj;
      const int done = (pm[k] == 0);
      // duals: col 0 (p[0]=i) by lane 0; cols 1..1024 by owning lane.
      if (lane == 0) u[i] += delta;
#pragma unroll
      for (int r = 0; r < 16; ++r) {
        const int j = 1 + lane + r * 64;
        if ((used_mask >> r) & 1u) {
          v_[r] -= delta;
          u[pm[j]] += delta;        // matched rows distinct -> no race
        } else {
          minv_[r] -= delta;
          if (j == k) used_mask |= (1u << r);
        }
      }
      WAVE_SYNC(); SCHED_FENCE();
      j0 = k;
      if (done) break;
    }
    WAVE_SYNC();
    if (lane == 0) {  // augment along the path
      int jj = j0;
      while (jj != 0) { int j1 = way[jj]; pm[jj] = pm[j1]; jj = j1; }
    }
    WAVE_SYNC(); SCHED_FENCE();
  }

  for (int j = 1 + lane; j < 1025; j += 64) {
    int r = pm[j];
    if (r > 0) idxl[r - 1] = j - 1;
  }
  WAVE_SYNC(); SCHED_FENCE();
  if (lane < NC) idx_out[(size_t)s * NC + lane] = (float)idxl[lane];
#pragma unroll
  for (int p = 0; p < 8; ++p) {
    int vi = p * 64 + lane;          // float4 index within sample (512 total)
    int r = vi >> 4, c4 = vi & 15;
    int ci = idxl[r];
    float4 qv = *(const float4*)&codebook[(size_t)ci * 64 + c4 * 4];
    *(float4*)&q_out[(size_t)s * NCD + r * 64 + c4 * 4] = qv;
  }
}

// ---------------------------------------------------------------------------
extern "C" void kernel_launch(void* const* d_in, const int* in_sizes, int n_in,
                              void* d_out, int out_size, void* d_ws, size_t ws_size,
                              hipStream_t stream) {
  (void)in_sizes; (void)n_in; (void)out_size; (void)ws_size;
  const float* x        = (const float*)d_in[0];
  const float* codebook = (const float*)d_in[1];
  const float* enc_w    = (const float*)d_in[2];
  const float* enc_b    = (const float*)d_in[3];
  const float* dec_w    = (const float*)d_in[4];
  const float* dec_b    = (const float*)d_in[5];

  float* out = (float*)d_out;
  float* r_out   = out;                       // [512][4096]
  float* q_out   = out + 2097152;             // [512][32][64]
  float* e_out   = out + 2097152 + 1048576;   // [512][32][64]
  float* idx_out = out + 2097152 + 2097152;   // [512][32] as float

  float* cost_ws = (float*)d_ws;              // [16384][1024] f32 = 64 MB

  // K1: e = x @ enc_w.T + enc_b   (M=512, N=2048, K=4096)
  gemm_nt_bias<<<dim3(BATCH / 64, NCD / 64), 256, 0, stream>>>(
      x, enc_w, enc_b, e_out, BATCH, NCD, HID);

  // K2a: batched distance matrix -> workspace
  k_cost<<<dim3(16384 / 64, CB / 256), 256, 0, stream>>>(
      e_out, codebook, cost_ws);

  // K2b: per-sample Hungarian + q gather (one wave per sample)
  k_assign<<<BATCH, 64, 0, stream>>>(cost_ws, codebook, q_out, idx_out);

  // K3: r = q @ dec_w.T + dec_b   (M=512, N=4096, K=2048)
  gemm_nt_bias<<<dim3(BATCH / 64, HID / 64), 256, 0, stream>>>(
      q_out, dec_w, dec_b, r_out, BATCH, HID, NCD);
}

// Round 5
// 397.167 us; speedup vs baseline: 1.8408x; 1.6023x over previous
//
#include <hip/hip_runtime.h>
#include <hip/hip_bf16.h>
#include <stdint.h>

// Sizes
#define BATCH 512
#define HID   4096
#define NC    32
#define CD    64
#define CB    1024
#define NCD   2048   // NC*CD

typedef unsigned short u16;
typedef unsigned int   u32;
typedef __attribute__((ext_vector_type(8))) short short8;  // 8 bf16
typedef __attribute__((ext_vector_type(4))) float f32x4;

#define WAVE_SYNC()  asm volatile("s_waitcnt lgkmcnt(0)" ::: "memory")
#define SCHED_FENCE() __builtin_amdgcn_sched_barrier(0)

__device__ inline u16 bf16_rne(float f) {
  u32 u = __builtin_bit_cast(u32, f);
  u32 r = u + 0x7FFFu + ((u >> 16) & 1u);
  return (u16)(r >> 16);
}
__device__ inline float bf16_f32(u16 h) {
  u32 u = ((u32)h) << 16;
  return __builtin_bit_cast(float, u);
}
__device__ inline void split3(float a, u16& h1, u16& h2, u16& h3) {
  h1 = bf16_rne(a);
  float r1 = a - bf16_f32(h1);
  h2 = bf16_rne(r1);
  float r2 = r1 - bf16_f32(h2);
  h3 = bf16_rne(r2);
}
__device__ inline f32x4 mfma16(short8 a, short8 b, f32x4 c) {
  return __builtin_amdgcn_mfma_f32_16x16x32_bf16(a, b, c, 0, 0, 0);
}
__device__ inline void gload_lds16(const u16* g, u16* l) {
  __builtin_amdgcn_global_load_lds(
      (const __attribute__((address_space(1))) u32*)(const void*)g,
      (__attribute__((address_space(3))) u32*)(void*)l, 16, 0, 0);
}

union H8 { u16 h[8]; short8 v; };

// ---------------------------------------------------------------------------
// conv_split3: f32 [ROWS][K] -> 3 bf16 fragment-blob arrays.
// Blob g = (row/16)*(K/32) + (k/32); lane l in blob holds
// src[rowfrag*16 + (l&15)][kstep*32 + (l>>4)*8 + 0..7]. 4 blobs per block.
// ---------------------------------------------------------------------------
template<int K>
__global__ __launch_bounds__(256) void conv_split3(
    const float* __restrict__ src, u16* __restrict__ d1,
    u16* __restrict__ d2, u16* __restrict__ d3) {
  const int t = threadIdx.x;
  const int g = blockIdx.x * 4 + (t >> 6);
  const int l = t & 63;
  const int n  = (g / (K / 32)) * 16 + (l & 15);
  const int k0 = (g % (K / 32)) * 32 + (l >> 4) * 8;
  const float* s = src + (size_t)n * K + k0;
  H8 o1, o2, o3;
#pragma unroll
  for (int i = 0; i < 8; ++i) split3(s[i], o1.h[i], o2.h[i], o3.h[i]);
  size_t off = (size_t)g * 512 + l * 8;
  *(short8*)(d1 + off) = o1.v;
  *(short8*)(d2 + off) = o2.v;
  *(short8*)(d3 + off) = o3.v;
}

template<int K>
__global__ __launch_bounds__(256) void conv_split1(
    const float* __restrict__ src, u16* __restrict__ d1) {
  const int t = threadIdx.x;
  const int g = blockIdx.x * 4 + (t >> 6);
  const int l = t & 63;
  const int n  = (g / (K / 32)) * 16 + (l & 15);
  const int k0 = (g % (K / 32)) * 32 + (l >> 4) * 8;
  const float* s = src + (size_t)n * K + k0;
  H8 o1;
#pragma unroll
  for (int i = 0; i < 8; ++i) o1.h[i] = bf16_rne(s[i]);
  *(short8*)(d1 + (size_t)g * 512 + l * 8) = o1.v;
}

// ---------------------------------------------------------------------------
// k1_gemm: partial[kz] = x[128-tile] @ enc_w^T[128-tile] over Ksub=1024,
// bf16x3 6-term emulation of f32. A (x) split in-kernel; B pre-split blobs.
// 128x128 tile, 8 waves (2x4), split-K=4. Partials f32 (reduced later).
// ---------------------------------------------------------------------------
__global__ __launch_bounds__(512) void k1_gemm(
    const float* __restrict__ A,
    const u16* __restrict__ B1, const u16* __restrict__ B2,
    const u16* __restrict__ B3, float* __restrict__ part) {
  __shared__ u16 As[3][8][64][8];   // [split][rowfrag][lane][8]
  __shared__ u16 Bs[3][8][64][8];   // [split][colfrag][lane][8]
  const int t = threadIdx.x;
  const int wid = t >> 6, lane = t & 63;
  const int wrow = wid >> 2, wcol = wid & 3;
  const int bm = blockIdx.x * 128;
  const int bn = blockIdx.y * 128;
  const int kz = blockIdx.z;
  const int kbase = kz * 1024;
  const int arow = t >> 2;          // 0..127 (16 rows per wave, coalesced)
  const int akc  = t & 3;           // k-chunk 0..3
  const float* aptr = A + (size_t)(bm + arow) * HID + kbase + akc * 8;
  const int arf = arow >> 4, all_ = (akc << 4) | (arow & 15);
  const size_t nf0 = (size_t)((bn >> 4) + wid);  // wave's B colfrag id

  f32x4 acc[4][2];
#pragma unroll
  for (int r = 0; r < 4; ++r)
#pragma unroll
    for (int c = 0; c < 2; ++c) acc[r][c] = (f32x4)0.f;

  for (int ks = 0; ks < 32; ++ks) {
    // A: f32 load -> 3-way split -> LDS blobs
    float v[8];
    *(f32x4*)&v[0] = *(const f32x4*)(aptr + ks * 32);
    *(f32x4*)&v[4] = *(const f32x4*)(aptr + ks * 32 + 4);
    // B: async global->LDS, one colfrag per wave, 3 splits
    {
      size_t gb = (nf0 * 128 + (size_t)((kbase >> 5) + ks)) * 512 + lane * 8;
      gload_lds16(B1 + gb, &Bs[0][wid][0][0]);
      gload_lds16(B2 + gb, &Bs[1][wid][0][0]);
      gload_lds16(B3 + gb, &Bs[2][wid][0][0]);
    }
    {
      H8 s1, s2, s3;
#pragma unroll
      for (int i = 0; i < 8; ++i) split3(v[i], s1.h[i], s2.h[i], s3.h[i]);
      *(short8*)&As[0][arf][all_][0] = s1.v;
      *(short8*)&As[1][arf][all_][0] = s2.v;
      *(short8*)&As[2][arf][all_][0] = s3.v;
    }
    __syncthreads();
    short8 a0[4], a1[4], a2[4], b0[2], b1[2], b2[2];
#pragma unroll
    for (int r = 0; r < 4; ++r) {
      a0[r] = *(const short8*)&As[0][wrow * 4 + r][lane][0];
      a1[r] = *(const short8*)&As[1][wrow * 4 + r][lane][0];
      a2[r] = *(const short8*)&As[2][wrow * 4 + r][lane][0];
    }
#pragma unroll
    for (int c = 0; c < 2; ++c) {
      b0[c] = *(const short8*)&Bs[0][wcol * 2 + c][lane][0];
      b1[c] = *(const short8*)&Bs[1][wcol * 2 + c][lane][0];
      b2[c] = *(const short8*)&Bs[2][wcol * 2 + c][lane][0];
    }
#pragma unroll
    for (int r = 0; r < 4; ++r)
#pragma unroll
      for (int c = 0; c < 2; ++c) {
        f32x4 d = acc[r][c];
        d = mfma16(a0[r], b0[c], d);
        d = mfma16(a0[r], b1[c], d);
        d = mfma16(a1[r], b0[c], d);
        d = mfma16(a1[r], b1[c], d);
        d = mfma16(a0[r], b2[c], d);
        d = mfma16(a2[r], b0[c], d);
        acc[r][c] = d;
      }
    __syncthreads();
  }
  float* P = part + (size_t)kz * BATCH * NCD;
#pragma unroll
  for (int r = 0; r < 4; ++r)
#pragma unroll
    for (int c = 0; c < 2; ++c) {
      int row = bm + wrow * 64 + r * 16 + (lane >> 4) * 4;
      int col = bn + wcol * 32 + c * 16 + (lane & 15);
#pragma unroll
      for (int i = 0; i < 4; ++i)
        P[(size_t)(row + i) * NCD + col] = acc[r][c][i];
    }
}

// ---------------------------------------------------------------------------
__global__ __launch_bounds__(256) void k_reduce_bias(
    const float* __restrict__ part, const float* __restrict__ bias,
    float* __restrict__ e) {
  size_t o = ((size_t)blockIdx.x * 256 + threadIdx.x) * 4;
  int n = (int)(o & (NCD - 1));
  f32x4 s = *(const f32x4*)(part + o);
  s += *(const f32x4*)(part + (size_t)1 * BATCH * NCD + o);
  s += *(const f32x4*)(part + (size_t)2 * BATCH * NCD + o);
  s += *(const f32x4*)(part + (size_t)3 * BATCH * NCD + o);
  s += *(const f32x4*)(bias + n);
  *(f32x4*)(e + o) = s;
}

// ---------------------------------------------------------------------------
// k3_gemm: r = q @ dec_w.T + dec_b, plain bf16 (within bf16-grid threshold).
// 64x128 tile, 8 waves (2x4), blobs pre-converted.
// ---------------------------------------------------------------------------
__global__ __launch_bounds__(512) void k3_gemm(
    const u16* __restrict__ Ab, const u16* __restrict__ Bb,
    const float* __restrict__ bias, float* __restrict__ C) {
  __shared__ u16 As[4][64][8];
  __shared__ u16 Bs[8][64][8];
  const int t = threadIdx.x;
  const int wid = t >> 6, lane = t & 63;
  const int wrow = wid >> 2, wcol = wid & 3;
  const int bm = blockIdx.x * 64, bn = blockIdx.y * 128;
  f32x4 acc[2][2];
#pragma unroll
  for (int r = 0; r < 2; ++r)
#pragma unroll
    for (int c = 0; c < 2; ++c) acc[r][c] = (f32x4)0.f;

  for (int ks = 0; ks < 64; ++ks) {
    {
      size_t gb = (((size_t)(bn >> 4) + wid) * 64 + ks) * 512 + lane * 8;
      gload_lds16(Bb + gb, &Bs[wid][0][0]);
      if (wid < 4) {
        size_t ga = (((size_t)(bm >> 4) + wid) * 64 + ks) * 512 + lane * 8;
        gload_lds16(Ab + ga, &As[wid][0][0]);
      }
    }
    __syncthreads();
    short8 a[2], b[2];
#pragma unroll
    for (int r = 0; r < 2; ++r) a[r] = *(const short8*)&As[wrow * 2 + r][lane][0];
#pragma unroll
    for (int c = 0; c < 2; ++c) b[c] = *(const short8*)&Bs[wcol * 2 + c][lane][0];
#pragma unroll
    for (int r = 0; r < 2; ++r)
#pragma unroll
      for (int c = 0; c < 2; ++c) acc[r][c] = mfma16(a[r], b[c], acc[r][c]);
    __syncthreads();
  }
#pragma unroll
  for (int r = 0; r < 2; ++r)
#pragma unroll
    for (int c = 0; c < 2; ++c) {
      int row = bm + wrow * 32 + r * 16 + (lane >> 4) * 4;
      int col = bn + wcol * 32 + c * 16 + (lane & 15);
      float bb = bias[col];
#pragma unroll
      for (int i = 0; i < 4; ++i)
        C[(size_t)(row + i) * HID + col] = acc[r][c][i] + bb;
    }
}

// ---------------------------------------------------------------------------
// k_cost: cost[r][c] = || e[r] - codebook[c] || (f32, unchanged from R3).
// ---------------------------------------------------------------------------
__global__ __launch_bounds__(256) void k_cost(
    const float* __restrict__ e_glob, const float* __restrict__ codebook,
    float* __restrict__ cost) {
  __shared__ float es[64][68];
  __shared__ float cs[64][68];
  __shared__ float enorm[64], cnorm[64];
  const int t = threadIdx.x;
  const int r0 = blockIdx.x * 64;
  const int c0 = blockIdx.y * 256;
  const int tx = t & 15, ty = t >> 4;
  {
    int row = t & 63, kq = t >> 6;
    const float* src = e_glob + (size_t)(r0 + row) * 64 + kq * 16;
#pragma unroll
    for (int i = 0; i < 4; ++i) {
      float4 v = *(const float4*)(src + i * 4);
      int kk = kq * 16 + i * 4;
      es[kk + 0][row] = v.x; es[kk + 1][row] = v.y;
      es[kk + 2][row] = v.z; es[kk + 3][row] = v.w;
    }
  }
  __syncthreads();
  if (t < 64) {
    float s = 0.f;
    for (int kk = 0; kk < 64; ++kk) { float x = es[kk][t]; s = fmaf(x, x, s); }
    enorm[t] = s;
  }
  for (int sub = 0; sub < 4; ++sub) {
    __syncthreads();
    {
      int col = t & 63, kq = t >> 6;
      const float* src = codebook + (size_t)(c0 + sub * 64 + col) * 64 + kq * 16;
#pragma unroll
      for (int i = 0; i < 4; ++i) {
        float4 v = *(const float4*)(src + i * 4);
        int kk = kq * 16 + i * 4;
        cs[kk + 0][col] = v.x; cs[kk + 1][col] = v.y;
        cs[kk + 2][col] = v.z; cs[kk + 3][col] = v.w;
      }
    }
    __syncthreads();
    if (t < 64) {
      float s = 0.f;
      for (int kk = 0; kk < 64; ++kk) { float x = cs[kk][t]; s = fmaf(x, x, s); }
      cnorm[t] = s;
    }
    __syncthreads();
    float dot[4][4] = {};
#pragma unroll 8
    for (int kk = 0; kk < 64; ++kk) {
      float4 a4 = *(const float4*)&es[kk][ty * 4];
      float4 b4 = *(const float4*)&cs[kk][tx * 4];
      float a_[4] = {a4.x, a4.y, a4.z, a4.w};
      float b_[4] = {b4.x, b4.y, b4.z, b4.w};
#pragma unroll
      for (int i = 0; i < 4; ++i)
#pragma unroll
        for (int j = 0; j < 4; ++j)
          dot[i][j] = fmaf(a_[i], b_[j], dot[i][j]);
    }
#pragma unroll
    for (int i = 0; i < 4; ++i) {
      int r = ty * 4 + i;
      float en = enorm[r];
      float4 o;
      o.x = sqrtf(fmaxf(en + cnorm[tx * 4 + 0] - 2.f * dot[i][0], 0.f));
      o.y = sqrtf(fmaxf(en + cnorm[tx * 4 + 1] - 2.f * dot[i][1], 0.f));
      o.z = sqrtf(fmaxf(en + cnorm[tx * 4 + 2] - 2.f * dot[i][2], 0.f));
      o.w = sqrtf(fmaxf(en + cnorm[tx * 4 + 3] - 2.f * dot[i][3], 0.f));
      *(float4*)&cost[(size_t)(r0 + r) * CB + c0 + sub * 64 + tx * 4] = o;
    }
  }
}

// ---------------------------------------------------------------------------
// k_assign: one wave per sample, JV with register state (unchanged from R3).
// ---------------------------------------------------------------------------
__global__ __launch_bounds__(64) void k_assign(
    const float* __restrict__ cost_g, const float* __restrict__ codebook,
    float* __restrict__ q_out, float* __restrict__ idx_out) {
  __shared__ double u[33];
  __shared__ unsigned short way[1025];
  __shared__ unsigned char pm[1025];
  __shared__ int idxl[32];
  const int lane = threadIdx.x;
  const int s = blockIdx.x;
  const float* __restrict__ cost = cost_g + (size_t)s * NC * CB;

  for (int j = lane; j < 1025; j += 64) pm[j] = 0;
  if (lane < 33) u[lane] = 0.0;
  double v_[16], minv_[16];
#pragma unroll
  for (int r = 0; r < 16; ++r) v_[r] = 0.0;
  WAVE_SYNC(); SCHED_FENCE();

  for (int i = 1; i <= NC; ++i) {
#pragma unroll
    for (int r = 0; r < 16; ++r) minv_[r] = 1e300;
    unsigned used_mask = 0;
    if (lane == 0) pm[0] = (unsigned char)i;
    WAVE_SYNC(); SCHED_FENCE();
    int j0 = 0;
    for (int guard = 0; guard < 1056; ++guard) {
      const int i0 = pm[j0];
      const double ui0 = u[i0];
      const float* crow = cost + (size_t)(i0 - 1) * CB - 1;
      double bv = 1e301; int bj = 1 << 20;
#pragma unroll
      for (int r = 0; r < 16; ++r) {
        const int j = 1 + lane + r * 64;
        if (!((used_mask >> r) & 1u)) {
          double cur = (double)crow[j] - ui0 - v_[r];
          if (cur < minv_[r]) { minv_[r] = cur; way[j] = (unsigned short)j0; }
          if (minv_[r] < bv) { bv = minv_[r]; bj = j; }
        }
      }
#pragma unroll
      for (int off = 1; off < 64; off <<= 1) {
        double ov = __shfl_xor(bv, off);
        int oj = __shfl_xor(bj, off);
        if (ov < bv || (ov == bv && oj < bj)) { bv = ov; bj = oj; }
      }
      const double delta = bv;
      const int k = bj;
      const int done = (pm[k] == 0);
      if (lane == 0) u[i] += delta;
#pragma unroll
      for (int r = 0; r < 16; ++r) {
        const int j = 1 + lane + r * 64;
        if ((used_mask >> r) & 1u) {
          v_[r] -= delta;
          u[pm[j]] += delta;
        } else {
          minv_[r] -= delta;
          if (j == k) used_mask |= (1u << r);
        }
      }
      WAVE_SYNC(); SCHED_FENCE();
      j0 = k;
      if (done) break;
    }
    WAVE_SYNC();
    if (lane == 0) {
      int jj = j0;
      while (jj != 0) { int j1 = way[jj]; pm[jj] = pm[j1]; jj = j1; }
    }
    WAVE_SYNC(); SCHED_FENCE();
  }

  for (int j = 1 + lane; j < 1025; j += 64) {
    int r = pm[j];
    if (r > 0) idxl[r - 1] = j - 1;
  }
  WAVE_SYNC(); SCHED_FENCE();
  if (lane < NC) idx_out[(size_t)s * NC + lane] = (float)idxl[lane];
#pragma unroll
  for (int p = 0; p < 8; ++p) {
    int vi = p * 64 + lane;
    int r = vi >> 4, c4 = vi & 15;
    int ci = idxl[r];
    float4 qv = *(const float4*)&codebook[(size_t)ci * 64 + c4 * 4];
    *(float4*)&q_out[(size_t)s * NCD + r * 64 + c4 * 4] = qv;
  }
}

// ---------------------------------------------------------------------------
extern "C" void kernel_launch(void* const* d_in, const int* in_sizes, int n_in,
                              void* d_out, int out_size, void* d_ws, size_t ws_size,
                              hipStream_t stream) {
  (void)in_sizes; (void)n_in; (void)out_size; (void)ws_size;
  const float* x        = (const float*)d_in[0];
  const float* codebook = (const float*)d_in[1];
  const float* enc_w    = (const float*)d_in[2];
  const float* enc_b    = (const float*)d_in[3];
  const float* dec_w    = (const float*)d_in[4];
  const float* dec_b    = (const float*)d_in[5];

  float* out = (float*)d_out;
  float* r_out   = out;                       // [512][4096]
  float* q_out   = out + 2097152;             // [512][32][64]
  float* e_out   = out + 2097152 + 1048576;   // [512][32][64]
  float* idx_out = out + 2097152 + 2097152;   // [512][32] as float

  // ws layout (64 MB, phase-disjoint):
  //  phase 1: enc_w blobs [0,48M), k1 partials [48M,64M)
  //  phase 2: cost [0,64M)
  //  phase 3: q blob [0,2M), dec_w blob [2M,18M)
  char* ws = (char*)d_ws;
  u16* B1 = (u16*)ws;
  u16* B2 = (u16*)(ws + (16u << 20));
  u16* B3 = (u16*)(ws + (32u << 20));
  float* part = (float*)(ws + (48u << 20));
  float* cost_ws = (float*)ws;
  u16* qb  = (u16*)ws;
  u16* dwb = (u16*)(ws + (2u << 20));

  // enc_w [2048][4096] -> 3 blob arrays; 16384 blobs / 4 per block
  conv_split3<HID><<<4096, 256, 0, stream>>>(enc_w, B1, B2, B3);
  // e partials (bf16x3 6-term), then reduce + bias
  k1_gemm<<<dim3(4, 16, 4), 512, 0, stream>>>(x, B1, B2, B3, part);
  k_reduce_bias<<<1024, 256, 0, stream>>>(part, enc_b, e_out);  // FIX: was 4096 (OOB)
  // distances + Hungarian
  k_cost<<<dim3(16384 / 64, CB / 256), 256, 0, stream>>>(e_out, codebook, cost_ws);
  k_assign<<<BATCH, 64, 0, stream>>>(cost_ws, codebook, q_out, idx_out);
  // decoder in plain bf16
  conv_split1<NCD><<<4096, 256, 0, stream>>>(dec_w, dwb);
  conv_split1<NCD><<<512, 256, 0, stream>>>(q_out, qb);
  k3_gemm<<<dim3(8, 32), 512, 0, stream>>>(qb, dwb, dec_b, r_out);
}

// Round 6
// 250.655 us; speedup vs baseline: 2.9168x; 1.5845x over previous
//
#include <hip/hip_runtime.h>
#include <hip/hip_bf16.h>
#include <stdint.h>

// Sizes
#define BATCH 512
#define HID   4096
#define NC    32
#define CD    64
#define CB    1024
#define NCD   2048   // NC*CD

typedef unsigned short u16;
typedef unsigned int   u32;
typedef __attribute__((ext_vector_type(8))) short short8;  // 8 bf16
typedef __attribute__((ext_vector_type(4))) float f32x4;

#define WAVE_SYNC()  asm volatile("s_waitcnt lgkmcnt(0)" ::: "memory")
#define SCHED_FENCE() __builtin_amdgcn_sched_barrier(0)

__device__ inline u16 bf16_rne(float f) {
  u32 u = __builtin_bit_cast(u32, f);
  u32 r = u + 0x7FFFu + ((u >> 16) & 1u);
  return (u16)(r >> 16);
}
__device__ inline float bf16_f32(u16 h) {
  u32 u = ((u32)h) << 16;
  return __builtin_bit_cast(float, u);
}
__device__ inline void split3(float a, u16& h1, u16& h2, u16& h3) {
  h1 = bf16_rne(a);
  float r1 = a - bf16_f32(h1);
  h2 = bf16_rne(r1);
  float r2 = r1 - bf16_f32(h2);
  h3 = bf16_rne(r2);
}
__device__ inline f32x4 mfma16(short8 a, short8 b, f32x4 c) {
  return __builtin_amdgcn_mfma_f32_16x16x32_bf16(a, b, c, 0, 0, 0);
}
__device__ inline void gload_lds16(const u16* g, u16* l) {
  __builtin_amdgcn_global_load_lds(
      (const __attribute__((address_space(1))) u32*)(const void*)g,
      (__attribute__((address_space(3))) u32*)(void*)l, 16, 0, 0);
}

union H8 { u16 h[8]; short8 v; };

// ---------------------------------------------------------------------------
// conv_split3: f32 [ROWS][K] -> 3 bf16 fragment-blob arrays.
// ---------------------------------------------------------------------------
template<int K>
__global__ __launch_bounds__(256) void conv_split3(
    const float* __restrict__ src, u16* __restrict__ d1,
    u16* __restrict__ d2, u16* __restrict__ d3) {
  const int t = threadIdx.x;
  const int g = blockIdx.x * 4 + (t >> 6);
  const int l = t & 63;
  const int n  = (g / (K / 32)) * 16 + (l & 15);
  const int k0 = (g % (K / 32)) * 32 + (l >> 4) * 8;
  const float* s = src + (size_t)n * K + k0;
  H8 o1, o2, o3;
#pragma unroll
  for (int i = 0; i < 8; ++i) split3(s[i], o1.h[i], o2.h[i], o3.h[i]);
  size_t off = (size_t)g * 512 + l * 8;
  *(short8*)(d1 + off) = o1.v;
  *(short8*)(d2 + off) = o2.v;
  *(short8*)(d3 + off) = o3.v;
}

template<int K>
__global__ __launch_bounds__(256) void conv_split1(
    const float* __restrict__ src, u16* __restrict__ d1) {
  const int t = threadIdx.x;
  const int g = blockIdx.x * 4 + (t >> 6);
  const int l = t & 63;
  const int n  = (g / (K / 32)) * 16 + (l & 15);
  const int k0 = (g % (K / 32)) * 32 + (l >> 4) * 8;
  const float* s = src + (size_t)n * K + k0;
  H8 o1;
#pragma unroll
  for (int i = 0; i < 8; ++i) o1.h[i] = bf16_rne(s[i]);
  *(short8*)(d1 + (size_t)g * 512 + l * 8) = o1.v;
}

// ---------------------------------------------------------------------------
// k1_gemm: bf16x3 6-term emulated-f32 GEMM, 128x128 tile, split-K=4.
// ---------------------------------------------------------------------------
__global__ __launch_bounds__(512) void k1_gemm(
    const float* __restrict__ A,
    const u16* __restrict__ B1, const u16* __restrict__ B2,
    const u16* __restrict__ B3, float* __restrict__ part) {
  __shared__ u16 As[3][8][64][8];   // [split][rowfrag][lane][8]
  __shared__ u16 Bs[3][8][64][8];   // [split][colfrag][lane][8]
  const int t = threadIdx.x;
  const int wid = t >> 6, lane = t & 63;
  const int wrow = wid >> 2, wcol = wid & 3;
  const int bm = blockIdx.x * 128;
  const int bn = blockIdx.y * 128;
  const int kz = blockIdx.z;
  const int kbase = kz * 1024;
  const int arow = t >> 2;
  const int akc  = t & 3;
  const float* aptr = A + (size_t)(bm + arow) * HID + kbase + akc * 8;
  const int arf = arow >> 4, all_ = (akc << 4) | (arow & 15);
  const size_t nf0 = (size_t)((bn >> 4) + wid);

  f32x4 acc[4][2];
#pragma unroll
  for (int r = 0; r < 4; ++r)
#pragma unroll
    for (int c = 0; c < 2; ++c) acc[r][c] = (f32x4)0.f;

  for (int ks = 0; ks < 32; ++ks) {
    float v[8];
    *(f32x4*)&v[0] = *(const f32x4*)(aptr + ks * 32);
    *(f32x4*)&v[4] = *(const f32x4*)(aptr + ks * 32 + 4);
    {
      size_t gb = (nf0 * 128 + (size_t)((kbase >> 5) + ks)) * 512 + lane * 8;
      gload_lds16(B1 + gb, &Bs[0][wid][0][0]);
      gload_lds16(B2 + gb, &Bs[1][wid][0][0]);
      gload_lds16(B3 + gb, &Bs[2][wid][0][0]);
    }
    {
      H8 s1, s2, s3;
#pragma unroll
      for (int i = 0; i < 8; ++i) split3(v[i], s1.h[i], s2.h[i], s3.h[i]);
      *(short8*)&As[0][arf][all_][0] = s1.v;
      *(short8*)&As[1][arf][all_][0] = s2.v;
      *(short8*)&As[2][arf][all_][0] = s3.v;
    }
    __syncthreads();
    short8 a0[4], a1[4], a2[4], b0[2], b1[2], b2[2];
#pragma unroll
    for (int r = 0; r < 4; ++r) {
      a0[r] = *(const short8*)&As[0][wrow * 4 + r][lane][0];
      a1[r] = *(const short8*)&As[1][wrow * 4 + r][lane][0];
      a2[r] = *(const short8*)&As[2][wrow * 4 + r][lane][0];
    }
#pragma unroll
    for (int c = 0; c < 2; ++c) {
      b0[c] = *(const short8*)&Bs[0][wcol * 2 + c][lane][0];
      b1[c] = *(const short8*)&Bs[1][wcol * 2 + c][lane][0];
      b2[c] = *(const short8*)&Bs[2][wcol * 2 + c][lane][0];
    }
#pragma unroll
    for (int r = 0; r < 4; ++r)
#pragma unroll
      for (int c = 0; c < 2; ++c) {
        f32x4 d = acc[r][c];
        d = mfma16(a0[r], b0[c], d);
        d = mfma16(a0[r], b1[c], d);
        d = mfma16(a1[r], b0[c], d);
        d = mfma16(a1[r], b1[c], d);
        d = mfma16(a0[r], b2[c], d);
        d = mfma16(a2[r], b0[c], d);
        acc[r][c] = d;
      }
    __syncthreads();
  }
  float* P = part + (size_t)kz * BATCH * NCD;
#pragma unroll
  for (int r = 0; r < 4; ++r)
#pragma unroll
    for (int c = 0; c < 2; ++c) {
      int row = bm + wrow * 64 + r * 16 + (lane >> 4) * 4;
      int col = bn + wcol * 32 + c * 16 + (lane & 15);
#pragma unroll
      for (int i = 0; i < 4; ++i)
        P[(size_t)(row + i) * NCD + col] = acc[r][c][i];
    }
}

// ---------------------------------------------------------------------------
__global__ __launch_bounds__(256) void k_reduce_bias(
    const float* __restrict__ part, const float* __restrict__ bias,
    float* __restrict__ e) {
  size_t o = ((size_t)blockIdx.x * 256 + threadIdx.x) * 4;
  int n = (int)(o & (NCD - 1));
  f32x4 s = *(const f32x4*)(part + o);
  s += *(const f32x4*)(part + (size_t)1 * BATCH * NCD + o);
  s += *(const f32x4*)(part + (size_t)2 * BATCH * NCD + o);
  s += *(const f32x4*)(part + (size_t)3 * BATCH * NCD + o);
  s += *(const f32x4*)(bias + n);
  *(f32x4*)(e + o) = s;
}

// ---------------------------------------------------------------------------
// k3_gemm: r = q @ dec_w.T + dec_b, plain bf16.
// ---------------------------------------------------------------------------
__global__ __launch_bounds__(512) void k3_gemm(
    const u16* __restrict__ Ab, const u16* __restrict__ Bb,
    const float* __restrict__ bias, float* __restrict__ C) {
  __shared__ u16 As[4][64][8];
  __shared__ u16 Bs[8][64][8];
  const int t = threadIdx.x;
  const int wid = t >> 6, lane = t & 63;
  const int wrow = wid >> 2, wcol = wid & 3;
  const int bm = blockIdx.x * 64, bn = blockIdx.y * 128;
  f32x4 acc[2][2];
#pragma unroll
  for (int r = 0; r < 2; ++r)
#pragma unroll
    for (int c = 0; c < 2; ++c) acc[r][c] = (f32x4)0.f;

  for (int ks = 0; ks < 64; ++ks) {
    {
      size_t gb = (((size_t)(bn >> 4) + wid) * 64 + ks) * 512 + lane * 8;
      gload_lds16(Bb + gb, &Bs[wid][0][0]);
      if (wid < 4) {
        size_t ga = (((size_t)(bm >> 4) + wid) * 64 + ks) * 512 + lane * 8;
        gload_lds16(Ab + ga, &As[wid][0][0]);
      }
    }
    __syncthreads();
    short8 a[2], b[2];
#pragma unroll
    for (int r = 0; r < 2; ++r) a[r] = *(const short8*)&As[wrow * 2 + r][lane][0];
#pragma unroll
    for (int c = 0; c < 2; ++c) b[c] = *(const short8*)&Bs[wcol * 2 + c][lane][0];
#pragma unroll
    for (int r = 0; r < 2; ++r)
#pragma unroll
      for (int c = 0; c < 2; ++c) acc[r][c] = mfma16(a[r], b[c], acc[r][c]);
    __syncthreads();
  }
#pragma unroll
  for (int r = 0; r < 2; ++r)
#pragma unroll
    for (int c = 0; c < 2; ++c) {
      int row = bm + wrow * 32 + r * 16 + (lane >> 4) * 4;
      int col = bn + wcol * 32 + c * 16 + (lane & 15);
      float bb = bias[col];
#pragma unroll
      for (int i = 0; i < 4; ++i)
        C[(size_t)(row + i) * HID + col] = acc[r][c][i] + bb;
    }
}

// ---------------------------------------------------------------------------
// k_cost: cost[r][c] = || e[r] - codebook[c] || (f32, unchanged).
// ---------------------------------------------------------------------------
__global__ __launch_bounds__(256) void k_cost(
    const float* __restrict__ e_glob, const float* __restrict__ codebook,
    float* __restrict__ cost) {
  __shared__ float es[64][68];
  __shared__ float cs[64][68];
  __shared__ float enorm[64], cnorm[64];
  const int t = threadIdx.x;
  const int r0 = blockIdx.x * 64;
  const int c0 = blockIdx.y * 256;
  const int tx = t & 15, ty = t >> 4;
  {
    int row = t & 63, kq = t >> 6;
    const float* src = e_glob + (size_t)(r0 + row) * 64 + kq * 16;
#pragma unroll
    for (int i = 0; i < 4; ++i) {
      float4 v = *(const float4*)(src + i * 4);
      int kk = kq * 16 + i * 4;
      es[kk + 0][row] = v.x; es[kk + 1][row] = v.y;
      es[kk + 2][row] = v.z; es[kk + 3][row] = v.w;
    }
  }
  __syncthreads();
  if (t < 64) {
    float s = 0.f;
    for (int kk = 0; kk < 64; ++kk) { float x = es[kk][t]; s = fmaf(x, x, s); }
    enorm[t] = s;
  }
  for (int sub = 0; sub < 4; ++sub) {
    __syncthreads();
    {
      int col = t & 63, kq = t >> 6;
      const float* src = codebook + (size_t)(c0 + sub * 64 + col) * 64 + kq * 16;
#pragma unroll
      for (int i = 0; i < 4; ++i) {
        float4 v = *(const float4*)(src + i * 4);
        int kk = kq * 16 + i * 4;
        cs[kk + 0][col] = v.x; cs[kk + 1][col] = v.y;
        cs[kk + 2][col] = v.z; cs[kk + 3][col] = v.w;
      }
    }
    __syncthreads();
    if (t < 64) {
      float s = 0.f;
      for (int kk = 0; kk < 64; ++kk) { float x = cs[kk][t]; s = fmaf(x, x, s); }
      cnorm[t] = s;
    }
    __syncthreads();
    float dot[4][4] = {};
#pragma unroll 8
    for (int kk = 0; kk < 64; ++kk) {
      float4 a4 = *(const float4*)&es[kk][ty * 4];
      float4 b4 = *(const float4*)&cs[kk][tx * 4];
      float a_[4] = {a4.x, a4.y, a4.z, a4.w};
      float b_[4] = {b4.x, b4.y, b4.z, b4.w};
#pragma unroll
      for (int i = 0; i < 4; ++i)
#pragma unroll
        for (int j = 0; j < 4; ++j)
          dot[i][j] = fmaf(a_[i], b_[j], dot[i][j]);
    }
#pragma unroll
    for (int i = 0; i < 4; ++i) {
      int r = ty * 4 + i;
      float en = enorm[r];
      float4 o;
      o.x = sqrtf(fmaxf(en + cnorm[tx * 4 + 0] - 2.f * dot[i][0], 0.f));
      o.y = sqrtf(fmaxf(en + cnorm[tx * 4 + 1] - 2.f * dot[i][1], 0.f));
      o.z = sqrtf(fmaxf(en + cnorm[tx * 4 + 2] - 2.f * dot[i][2], 0.f));
      o.w = sqrtf(fmaxf(en + cnorm[tx * 4 + 3] - 2.f * dot[i][3], 0.f));
      *(float4*)&cost[(size_t)(r0 + r) * CB + c0 + sub * 64 + tx * 4] = o;
    }
  }
}

// ---------------------------------------------------------------------------
// k_assign: one wave per sample. JV with ALL state in registers:
//  - v/minv/way/pm: 16 cols per lane (statically indexed)
//  - u: lane-indexed (lane l holds u[l]); read via shfl; update via row-mask
//  - cost rows: phase-first row prefetched into registers
// No LDS in the hot loop -> no lgkmcnt waits. f64 ops identical to numpy ref.
// ---------------------------------------------------------------------------
__global__ __launch_bounds__(64) void k_assign(
    const float* __restrict__ cost_g, const float* __restrict__ codebook,
    float* __restrict__ q_out, float* __restrict__ idx_out) {
  __shared__ int idxl[32];
  const int lane = threadIdx.x;
  const int s = blockIdx.x;
  const float* __restrict__ cost = cost_g + (size_t)s * NC * CB;

  double v_[16], minv_[16];
  u32 way_[16], pm_[16];
  double u_val = 0.0;                 // lane l holds u[l] (rows 1..32)
#pragma unroll
  for (int r = 0; r < 16; ++r) { v_[r] = 0.0; pm_[r] = 0; }

  float pf[16];                       // prefetched row for next phase
#pragma unroll
  for (int r = 0; r < 16; ++r) pf[r] = cost[r * 64 + lane];   // row 0 (phase 1)

  for (int i = 1; i <= NC; ++i) {
#pragma unroll
    for (int r = 0; r < 16; ++r) minv_[r] = 1e300;
    u32 col_used = 0;
    unsigned long long rowmask = 0ull;
    int j0 = 0;
    int i0 = i;
    int first = 1;
    for (int guard = 0; guard < 1056; ++guard) {
      rowmask |= (1ull << i0);
      const double ui0 = __shfl(u_val, i0);
      float cc[16];
      if (first) {
#pragma unroll
        for (int r = 0; r < 16; ++r) cc[r] = pf[r];
        if (i < NC) {                 // prefetch next phase's row i (0-based)
#pragma unroll
          for (int r = 0; r < 16; ++r)
            pf[r] = cost[(size_t)i * CB + r * 64 + lane];
        }
        first = 0;
      } else {
        const float* crow = cost + (size_t)(i0 - 1) * CB;
#pragma unroll
        for (int r = 0; r < 16; ++r) cc[r] = crow[r * 64 + lane];
      }
      double bv = 1e301; int bj = 1 << 20;
#pragma unroll
      for (int r = 0; r < 16; ++r) {
        const int j = 1 + lane + r * 64;
        if (!((col_used >> r) & 1u)) {
          double cur = (double)cc[r] - ui0 - v_[r];
          if (cur < minv_[r]) { minv_[r] = cur; way_[r] = (u32)j0; }
          if (minv_[r] < bv) { bv = minv_[r]; bj = j; }
        }
      }
      // butterfly all-reduce: (min value, lowest j on ties)
#pragma unroll
      for (int off = 1; off < 64; off <<= 1) {
        double ov = __shfl_xor(bv, off);
        int oj = __shfl_xor(bj, off);
        if (ov < bv || (ov == bv && oj < bj)) { bv = ov; bj = oj; }
      }
      const double delta = bv;
      const int k = bj;
      // dual updates (u via row-mask, v/minv per-lane)
      if ((rowmask >> lane) & 1ull) u_val += delta;
#pragma unroll
      for (int r = 0; r < 16; ++r) {
        const int j = 1 + lane + r * 64;
        if ((col_used >> r) & 1u) v_[r] -= delta;
        else {
          minv_[r] -= delta;
          if (j == k) col_used |= (1u << r);
        }
      }
      // i0' = pm[k] (owner-lane extract + broadcast); done if 0
      const int rk = (k - 1) >> 6, kl = (k - 1) & 63;
      u32 sel = 0;
#pragma unroll
      for (int r = 0; r < 16; ++r) if (r == rk) sel = pm_[r];
      const int pmk = __shfl((int)sel, kl);
      j0 = k;
      if (pmk == 0) break;
      i0 = pmk;
    }
    // augment along the path (register pm/way, wave-uniform walk)
    int jj = j0;
    while (jj != 0) {
      const int rj = (jj - 1) >> 6, lj = (jj - 1) & 63;
      u32 wsel = 0;
#pragma unroll
      for (int r = 0; r < 16; ++r) if (r == rj) wsel = way_[r];
      const int j1 = __shfl((int)wsel, lj);
      int newpm;
      if (j1 == 0) newpm = i;
      else {
        const int r1 = (j1 - 1) >> 6, l1 = (j1 - 1) & 63;
        u32 psel = 0;
#pragma unroll
        for (int r = 0; r < 16; ++r) if (r == r1) psel = pm_[r];
        newpm = __shfl((int)psel, l1);
      }
#pragma unroll
      for (int r = 0; r < 16; ++r)
        if (lane == lj && r == rj) pm_[r] = (u32)newpm;
      jj = j1;
    }
  }

  // emit indices
#pragma unroll
  for (int r = 0; r < 16; ++r)
    if (pm_[r] > 0) idxl[pm_[r] - 1] = lane + r * 64;
  WAVE_SYNC(); SCHED_FENCE();
  if (lane < NC) idx_out[(size_t)s * NC + lane] = (float)idxl[lane];
#pragma unroll
  for (int p = 0; p < 8; ++p) {
    int vi = p * 64 + lane;
    int r = vi >> 4, c4 = vi & 15;
    int ci = idxl[r];
    float4 qv = *(const float4*)&codebook[(size_t)ci * 64 + c4 * 4];
    *(float4*)&q_out[(size_t)s * NCD + r * 64 + c4 * 4] = qv;
  }
}

// ---------------------------------------------------------------------------
extern "C" void kernel_launch(void* const* d_in, const int* in_sizes, int n_in,
                              void* d_out, int out_size, void* d_ws, size_t ws_size,
                              hipStream_t stream) {
  (void)in_sizes; (void)n_in; (void)out_size; (void)ws_size;
  const float* x        = (const float*)d_in[0];
  const float* codebook = (const float*)d_in[1];
  const float* enc_w    = (const float*)d_in[2];
  const float* enc_b    = (const float*)d_in[3];
  const float* dec_w    = (const float*)d_in[4];
  const float* dec_b    = (const float*)d_in[5];

  float* out = (float*)d_out;
  float* r_out   = out;                       // [512][4096]
  float* q_out   = out + 2097152;             // [512][32][64]
  float* e_out   = out + 2097152 + 1048576;   // [512][32][64]
  float* idx_out = out + 2097152 + 2097152;   // [512][32] as float

  // ws layout (64 MB, phase-disjoint):
  //  phase 1: enc_w blobs [0,48M), k1 partials [48M,64M)
  //  phase 2: cost [0,64M)
  //  phase 3: q blob [0,2M), dec_w blob [2M,18M)
  char* ws = (char*)d_ws;
  u16* B1 = (u16*)ws;
  u16* B2 = (u16*)(ws + (16u << 20));
  u16* B3 = (u16*)(ws + (32u << 20));
  float* part = (float*)(ws + (48u << 20));
  float* cost_ws = (float*)ws;
  u16* qb  = (u16*)ws;
  u16* dwb = (u16*)(ws + (2u << 20));

  conv_split3<HID><<<4096, 256, 0, stream>>>(enc_w, B1, B2, B3);
  k1_gemm<<<dim3(4, 16, 4), 512, 0, stream>>>(x, B1, B2, B3, part);
  k_reduce_bias<<<1024, 256, 0, stream>>>(part, enc_b, e_out);
  k_cost<<<dim3(16384 / 64, CB / 256), 256, 0, stream>>>(e_out, codebook, cost_ws);
  k_assign<<<BATCH, 64, 0, stream>>>(cost_ws, codebook, q_out, idx_out);
  conv_split1<NCD><<<4096, 256, 0, stream>>>(dec_w, dwb);
  conv_split1<NCD><<<512, 256, 0, stream>>>(q_out, qb);
  k3_gemm<<<dim3(8, 32), 512, 0, stream>>>(qb, dwb, dec_b, r_out);
}

// Round 7
// 232.236 us; speedup vs baseline: 3.1481x; 1.0793x over previous
//
#include <hip/hip_runtime.h>
#include <hip/hip_bf16.h>
#include <stdint.h>

// Sizes
#define BATCH 512
#define HID   4096
#define NC    32
#define CD    64
#define CB    1024
#define NCD   2048   // NC*CD

typedef unsigned short u16;
typedef unsigned int   u32;
typedef __attribute__((ext_vector_type(8))) short short8;  // 8 bf16
typedef __attribute__((ext_vector_type(4))) float f32x4;

#define WAVE_SYNC()  asm volatile("s_waitcnt lgkmcnt(0)" ::: "memory")
#define SCHED_FENCE() __builtin_amdgcn_sched_barrier(0)

__device__ inline u16 bf16_rne(float f) {
  u32 u = __builtin_bit_cast(u32, f);
  u32 r = u + 0x7FFFu + ((u >> 16) & 1u);
  return (u16)(r >> 16);
}
__device__ inline float bf16_f32(u16 h) {
  u32 u = ((u32)h) << 16;
  return __builtin_bit_cast(float, u);
}
__device__ inline void split3(float a, u16& h1, u16& h2, u16& h3) {
  h1 = bf16_rne(a);
  float r1 = a - bf16_f32(h1);
  h2 = bf16_rne(r1);
  float r2 = r1 - bf16_f32(h2);
  h3 = bf16_rne(r2);
}
__device__ inline f32x4 mfma16(short8 a, short8 b, f32x4 c) {
  return __builtin_amdgcn_mfma_f32_16x16x32_bf16(a, b, c, 0, 0, 0);
}
__device__ inline void gload_lds16(const u16* g, u16* l) {
  __builtin_amdgcn_global_load_lds(
      (const __attribute__((address_space(1))) u32*)(const void*)g,
      (__attribute__((address_space(3))) u32*)(void*)l, 16, 0, 0);
}

union H8 { u16 h[8]; short8 v; };

// ---------------------------------------------------------------------------
// conv_split3: f32 [ROWS][K] -> 3 bf16 fragment-blob arrays.
// ---------------------------------------------------------------------------
template<int K>
__global__ __launch_bounds__(256) void conv_split3(
    const float* __restrict__ src, u16* __restrict__ d1,
    u16* __restrict__ d2, u16* __restrict__ d3) {
  const int t = threadIdx.x;
  const int g = blockIdx.x * 4 + (t >> 6);
  const int l = t & 63;
  const int n  = (g / (K / 32)) * 16 + (l & 15);
  const int k0 = (g % (K / 32)) * 32 + (l >> 4) * 8;
  const float* s = src + (size_t)n * K + k0;
  H8 o1, o2, o3;
#pragma unroll
  for (int i = 0; i < 8; ++i) split3(s[i], o1.h[i], o2.h[i], o3.h[i]);
  size_t off = (size_t)g * 512 + l * 8;
  *(short8*)(d1 + off) = o1.v;
  *(short8*)(d2 + off) = o2.v;
  *(short8*)(d3 + off) = o3.v;
}

template<int K>
__global__ __launch_bounds__(256) void conv_split1(
    const float* __restrict__ src, u16* __restrict__ d1) {
  const int t = threadIdx.x;
  const int g = blockIdx.x * 4 + (t >> 6);
  const int l = t & 63;
  const int n  = (g / (K / 32)) * 16 + (l & 15);
  const int k0 = (g % (K / 32)) * 32 + (l >> 4) * 8;
  const float* s = src + (size_t)n * K + k0;
  H8 o1;
#pragma unroll
  for (int i = 0; i < 8; ++i) o1.h[i] = bf16_rne(s[i]);
  *(short8*)(d1 + (size_t)g * 512 + l * 8) = o1.v;
}

// ---------------------------------------------------------------------------
// k1_gemm: bf16x3 6-term emulated-f32 GEMM, 128x128 tile, split-K=4.
// Double-buffered LDS (prefetch ks+1 before compute ks); As slot XOR-swizzled
// (write AND read) to break the 4-way ds_write_b128 bank conflict.
// ---------------------------------------------------------------------------
__global__ __launch_bounds__(512) void k1_gemm(
    const float* __restrict__ A,
    const u16* __restrict__ B1, const u16* __restrict__ B2,
    const u16* __restrict__ B3, float* __restrict__ part) {
  __shared__ u16 As[2][3][8][64][8];   // [buf][split][rowfrag][slot][8]
  __shared__ u16 Bs[2][3][8][64][8];   // [buf][split][colfrag][lane][8]
  const int t = threadIdx.x;
  const int wid = t >> 6, lane = t & 63;
  const int wrow = wid >> 2, wcol = wid & 3;
  const int bm = blockIdx.x * 128;
  const int bn = blockIdx.y * 128;
  const int kz = blockIdx.z;
  const int kbase = kz * 1024;
  const int arow = t >> 2;
  const int akc  = t & 3;
  const float* aptr = A + (size_t)(bm + arow) * HID + kbase + akc * 8;
  const int arf = arow >> 4;
  const int p_w = (akc << 4) | (arow & 15);
  const int s_w = p_w ^ ((p_w >> 4) & 3);    // swizzled write slot
  const int s_r = lane ^ ((lane >> 4) & 3);  // swizzled read slot (same map)
  const size_t nf0 = (size_t)((bn >> 4) + wid);

  f32x4 acc[4][2];
#pragma unroll
  for (int r = 0; r < 4; ++r)
#pragma unroll
    for (int c = 0; c < 2; ++c) acc[r][c] = (f32x4)0.f;

  // prologue: stage ks=0 into buf 0
  {
    float va[8];
    *(f32x4*)&va[0] = *(const f32x4*)(aptr);
    *(f32x4*)&va[4] = *(const f32x4*)(aptr + 4);
    size_t gb = (nf0 * 128 + (size_t)(kbase >> 5)) * 512 + lane * 8;
    gload_lds16(B1 + gb, &Bs[0][0][wid][0][0]);
    gload_lds16(B2 + gb, &Bs[0][1][wid][0][0]);
    gload_lds16(B3 + gb, &Bs[0][2][wid][0][0]);
    H8 s1, s2, s3;
#pragma unroll
    for (int i = 0; i < 8; ++i) split3(va[i], s1.h[i], s2.h[i], s3.h[i]);
    *(short8*)&As[0][0][arf][s_w][0] = s1.v;
    *(short8*)&As[0][1][arf][s_w][0] = s2.v;
    *(short8*)&As[0][2][arf][s_w][0] = s3.v;
  }
  __syncthreads();

  for (int ks = 0; ks < 32; ++ks) {
    const int cur = ks & 1, nxt = cur ^ 1;
    // prefetch ks+1 (A to regs, B to LDS[nxt]) BEFORE compute of ks
    float vb[8];
    if (ks < 31) {
      *(f32x4*)&vb[0] = *(const f32x4*)(aptr + (ks + 1) * 32);
      *(f32x4*)&vb[4] = *(const f32x4*)(aptr + (ks + 1) * 32 + 4);
      size_t gb = (nf0 * 128 + (size_t)((kbase >> 5) + ks + 1)) * 512 + lane * 8;
      gload_lds16(B1 + gb, &Bs[nxt][0][wid][0][0]);
      gload_lds16(B2 + gb, &Bs[nxt][1][wid][0][0]);
      gload_lds16(B3 + gb, &Bs[nxt][2][wid][0][0]);
    }
    // compute on buf[cur]
    short8 a0[4], a1[4], a2[4], b0[2], b1[2], b2[2];
#pragma unroll
    for (int r = 0; r < 4; ++r) {
      a0[r] = *(const short8*)&As[cur][0][wrow * 4 + r][s_r][0];
      a1[r] = *(const short8*)&As[cur][1][wrow * 4 + r][s_r][0];
      a2[r] = *(const short8*)&As[cur][2][wrow * 4 + r][s_r][0];
    }
#pragma unroll
    for (int c = 0; c < 2; ++c) {
      b0[c] = *(const short8*)&Bs[cur][0][wcol * 2 + c][lane][0];
      b1[c] = *(const short8*)&Bs[cur][1][wcol * 2 + c][lane][0];
      b2[c] = *(const short8*)&Bs[cur][2][wcol * 2 + c][lane][0];
    }
#pragma unroll
    for (int r = 0; r < 4; ++r)
#pragma unroll
      for (int c = 0; c < 2; ++c) {
        f32x4 d = acc[r][c];
        d = mfma16(a0[r], b0[c], d);
        d = mfma16(a0[r], b1[c], d);
        d = mfma16(a1[r], b0[c], d);
        d = mfma16(a1[r], b1[c], d);
        d = mfma16(a0[r], b2[c], d);
        d = mfma16(a2[r], b0[c], d);
        acc[r][c] = d;
      }
    // split + write As[nxt] (compiler waits vmcnt for vb here, after MFMAs)
    if (ks < 31) {
      H8 s1, s2, s3;
#pragma unroll
      for (int i = 0; i < 8; ++i) split3(vb[i], s1.h[i], s2.h[i], s3.h[i]);
      *(short8*)&As[nxt][0][arf][s_w][0] = s1.v;
      *(short8*)&As[nxt][1][arf][s_w][0] = s2.v;
      *(short8*)&As[nxt][2][arf][s_w][0] = s3.v;
    }
    __syncthreads();
  }
  float* P = part + (size_t)kz * BATCH * NCD;
#pragma unroll
  for (int r = 0; r < 4; ++r)
#pragma unroll
    for (int c = 0; c < 2; ++c) {
      int row = bm + wrow * 64 + r * 16 + (lane >> 4) * 4;
      int col = bn + wcol * 32 + c * 16 + (lane & 15);
#pragma unroll
      for (int i = 0; i < 4; ++i)
        P[(size_t)(row + i) * NCD + col] = acc[r][c][i];
    }
}

// ---------------------------------------------------------------------------
__global__ __launch_bounds__(256) void k_reduce_bias(
    const float* __restrict__ part, const float* __restrict__ bias,
    float* __restrict__ e) {
  size_t o = ((size_t)blockIdx.x * 256 + threadIdx.x) * 4;
  int n = (int)(o & (NCD - 1));
  f32x4 s = *(const f32x4*)(part + o);
  s += *(const f32x4*)(part + (size_t)1 * BATCH * NCD + o);
  s += *(const f32x4*)(part + (size_t)2 * BATCH * NCD + o);
  s += *(const f32x4*)(part + (size_t)3 * BATCH * NCD + o);
  s += *(const f32x4*)(bias + n);
  *(f32x4*)(e + o) = s;
}

// ---------------------------------------------------------------------------
// k3_gemm: r = q @ dec_w.T + dec_b, plain bf16.
// ---------------------------------------------------------------------------
__global__ __launch_bounds__(512) void k3_gemm(
    const u16* __restrict__ Ab, const u16* __restrict__ Bb,
    const float* __restrict__ bias, float* __restrict__ C) {
  __shared__ u16 As[4][64][8];
  __shared__ u16 Bs[8][64][8];
  const int t = threadIdx.x;
  const int wid = t >> 6, lane = t & 63;
  const int wrow = wid >> 2, wcol = wid & 3;
  const int bm = blockIdx.x * 64, bn = blockIdx.y * 128;
  f32x4 acc[2][2];
#pragma unroll
  for (int r = 0; r < 2; ++r)
#pragma unroll
    for (int c = 0; c < 2; ++c) acc[r][c] = (f32x4)0.f;

  for (int ks = 0; ks < 64; ++ks) {
    {
      size_t gb = (((size_t)(bn >> 4) + wid) * 64 + ks) * 512 + lane * 8;
      gload_lds16(Bb + gb, &Bs[wid][0][0]);
      if (wid < 4) {
        size_t ga = (((size_t)(bm >> 4) + wid) * 64 + ks) * 512 + lane * 8;
        gload_lds16(Ab + ga, &As[wid][0][0]);
      }
    }
    __syncthreads();
    short8 a[2], b[2];
#pragma unroll
    for (int r = 0; r < 2; ++r) a[r] = *(const short8*)&As[wrow * 2 + r][lane][0];
#pragma unroll
    for (int c = 0; c < 2; ++c) b[c] = *(const short8*)&Bs[wcol * 2 + c][lane][0];
#pragma unroll
    for (int r = 0; r < 2; ++r)
#pragma unroll
      for (int c = 0; c < 2; ++c) acc[r][c] = mfma16(a[r], b[c], acc[r][c]);
    __syncthreads();
  }
#pragma unroll
  for (int r = 0; r < 2; ++r)
#pragma unroll
    for (int c = 0; c < 2; ++c) {
      int row = bm + wrow * 32 + r * 16 + (lane >> 4) * 4;
      int col = bn + wcol * 32 + c * 16 + (lane & 15);
      float bb = bias[col];
#pragma unroll
      for (int i = 0; i < 4; ++i)
        C[(size_t)(row + i) * HID + col] = acc[r][c][i] + bb;
    }
}

// ---------------------------------------------------------------------------
// k_cost: cost[r][c] = || e[r] - codebook[c] || (f32, unchanged).
// ---------------------------------------------------------------------------
__global__ __launch_bounds__(256) void k_cost(
    const float* __restrict__ e_glob, const float* __restrict__ codebook,
    float* __restrict__ cost) {
  __shared__ float es[64][68];
  __shared__ float cs[64][68];
  __shared__ float enorm[64], cnorm[64];
  const int t = threadIdx.x;
  const int r0 = blockIdx.x * 64;
  const int c0 = blockIdx.y * 256;
  const int tx = t & 15, ty = t >> 4;
  {
    int row = t & 63, kq = t >> 6;
    const float* src = e_glob + (size_t)(r0 + row) * 64 + kq * 16;
#pragma unroll
    for (int i = 0; i < 4; ++i) {
      float4 v = *(const float4*)(src + i * 4);
      int kk = kq * 16 + i * 4;
      es[kk + 0][row] = v.x; es[kk + 1][row] = v.y;
      es[kk + 2][row] = v.z; es[kk + 3][row] = v.w;
    }
  }
  __syncthreads();
  if (t < 64) {
    float s = 0.f;
    for (int kk = 0; kk < 64; ++kk) { float x = es[kk][t]; s = fmaf(x, x, s); }
    enorm[t] = s;
  }
  for (int sub = 0; sub < 4; ++sub) {
    __syncthreads();
    {
      int col = t & 63, kq = t >> 6;
      const float* src = codebook + (size_t)(c0 + sub * 64 + col) * 64 + kq * 16;
#pragma unroll
      for (int i = 0; i < 4; ++i) {
        float4 v = *(const float4*)(src + i * 4);
        int kk = kq * 16 + i * 4;
        cs[kk + 0][col] = v.x; cs[kk + 1][col] = v.y;
        cs[kk + 2][col] = v.z; cs[kk + 3][col] = v.w;
      }
    }
    __syncthreads();
    if (t < 64) {
      float s = 0.f;
      for (int kk = 0; kk < 64; ++kk) { float x = cs[kk][t]; s = fmaf(x, x, s); }
      cnorm[t] = s;
    }
    __syncthreads();
    float dot[4][4] = {};
#pragma unroll 8
    for (int kk = 0; kk < 64; ++kk) {
      float4 a4 = *(const float4*)&es[kk][ty * 4];
      float4 b4 = *(const float4*)&cs[kk][tx * 4];
      float a_[4] = {a4.x, a4.y, a4.z, a4.w};
      float b_[4] = {b4.x, b4.y, b4.z, b4.w};
#pragma unroll
      for (int i = 0; i < 4; ++i)
#pragma unroll
        for (int j = 0; j < 4; ++j)
          dot[i][j] = fmaf(a_[i], b_[j], dot[i][j]);
    }
#pragma unroll
    for (int i = 0; i < 4; ++i) {
      int r = ty * 4 + i;
      float en = enorm[r];
      float4 o;
      o.x = sqrtf(fmaxf(en + cnorm[tx * 4 + 0] - 2.f * dot[i][0], 0.f));
      o.y = sqrtf(fmaxf(en + cnorm[tx * 4 + 1] - 2.f * dot[i][1], 0.f));
      o.z = sqrtf(fmaxf(en + cnorm[tx * 4 + 2] - 2.f * dot[i][2], 0.f));
      o.w = sqrtf(fmaxf(en + cnorm[tx * 4 + 3] - 2.f * dot[i][3], 0.f));
      *(float4*)&cost[(size_t)(r0 + r) * CB + c0 + sub * 64 + tx * 4] = o;
    }
  }
}

// ---------------------------------------------------------------------------
// k_assign: one wave per sample. JV with ALL state in registers.
// __launch_bounds__(64,1) -> full VGPR budget, no scratch spills.
// way/pm packed into one u32 per column (low16 = way, high16 = pm).
// ---------------------------------------------------------------------------
__global__ __launch_bounds__(64, 1) void k_assign(
    const float* __restrict__ cost_g, const float* __restrict__ codebook,
    float* __restrict__ q_out, float* __restrict__ idx_out) {
  __shared__ int idxl[32];
  const int lane = threadIdx.x;
  const int s = blockIdx.x;
  const float* __restrict__ cost = cost_g + (size_t)s * NC * CB;

  double v_[16], minv_[16];
  u32 wp_[16];                        // low16 = way, high16 = pm
  double u_val = 0.0;                 // lane l holds u[l] (rows 1..32)
#pragma unroll
  for (int r = 0; r < 16; ++r) { v_[r] = 0.0; wp_[r] = 0; }

  float pf[16];                       // prefetched row for next phase
#pragma unroll
  for (int r = 0; r < 16; ++r) pf[r] = cost[r * 64 + lane];   // row 0 (phase 1)

  for (int i = 1; i <= NC; ++i) {
#pragma unroll
    for (int r = 0; r < 16; ++r) minv_[r] = 1e300;
    u32 col_used = 0;
    unsigned long long rowmask = 0ull;
    int j0 = 0;
    int i0 = i;
    int first = 1;
    for (int guard = 0; guard < 1056; ++guard) {
      rowmask |= (1ull << i0);
      const double ui0 = __shfl(u_val, i0);
      float cc[16];
      if (first) {
#pragma unroll
        for (int r = 0; r < 16; ++r) cc[r] = pf[r];
        if (i < NC) {                 // prefetch next phase's row i (0-based)
#pragma unroll
          for (int r = 0; r < 16; ++r)
            pf[r] = cost[(size_t)i * CB + r * 64 + lane];
        }
        first = 0;
      } else {
        const float* crow = cost + (size_t)(i0 - 1) * CB;
#pragma unroll
        for (int r = 0; r < 16; ++r) cc[r] = crow[r * 64 + lane];
      }
      double bv = 1e301; int bj = 1 << 20;
#pragma unroll
      for (int r = 0; r < 16; ++r) {
        const int j = 1 + lane + r * 64;
        if (!((col_used >> r) & 1u)) {
          double cur = (double)cc[r] - ui0 - v_[r];
          if (cur < minv_[r]) { minv_[r] = cur; wp_[r] = (wp_[r] & 0xFFFF0000u) | (u32)j0; }
          if (minv_[r] < bv) { bv = minv_[r]; bj = j; }
        }
      }
      // butterfly all-reduce: (min value, lowest j on ties)
#pragma unroll
      for (int off = 1; off < 64; off <<= 1) {
        double ov = __shfl_xor(bv, off);
        int oj = __shfl_xor(bj, off);
        if (ov < bv || (ov == bv && oj < bj)) { bv = ov; bj = oj; }
      }
      const double delta = bv;
      const int k = bj;
      // dual updates (u via row-mask, v/minv per-lane)
      if ((rowmask >> lane) & 1ull) u_val += delta;
#pragma unroll
      for (int r = 0; r < 16; ++r) {
        const int j = 1 + lane + r * 64;
        if ((col_used >> r) & 1u) v_[r] -= delta;
        else {
          minv_[r] -= delta;
          if (j == k) col_used |= (1u << r);
        }
      }
      // i0' = pm[k] (owner-lane extract + broadcast); done if 0
      const int rk = (k - 1) >> 6, kl = (k - 1) & 63;
      u32 sel = 0;
#pragma unroll
      for (int r = 0; r < 16; ++r) if (r == rk) sel = wp_[r];
      const int pmk = ((u32)__shfl((int)sel, kl)) >> 16;
      j0 = k;
      if (pmk == 0) break;
      i0 = pmk;
    }
    // augment along the path (register wp, wave-uniform walk)
    int jj = j0;
    while (jj != 0) {
      const int rj = (jj - 1) >> 6, lj = (jj - 1) & 63;
      u32 wsel = 0;
#pragma unroll
      for (int r = 0; r < 16; ++r) if (r == rj) wsel = wp_[r];
      const int j1 = ((u32)__shfl((int)wsel, lj)) & 0xFFFFu;
      int newpm;
      if (j1 == 0) newpm = i;
      else {
        const int r1 = (j1 - 1) >> 6, l1 = (j1 - 1) & 63;
        u32 psel = 0;
#pragma unroll
        for (int r = 0; r < 16; ++r) if (r == r1) psel = wp_[r];
        newpm = ((u32)__shfl((int)psel, l1)) >> 16;
      }
#pragma unroll
      for (int r = 0; r < 16; ++r)
        if (lane == lj && r == rj) wp_[r] = (wp_[r] & 0xFFFFu) | ((u32)newpm << 16);
      jj = j1;
    }
  }

  // emit indices
#pragma unroll
  for (int r = 0; r < 16; ++r) {
    const u32 pm = wp_[r] >> 16;
    if (pm > 0) idxl[pm - 1] = lane + r * 64;
  }
  WAVE_SYNC(); SCHED_FENCE();
  if (lane < NC) idx_out[(size_t)s * NC + lane] = (float)idxl[lane];
#pragma unroll
  for (int p = 0; p < 8; ++p) {
    int vi = p * 64 + lane;
    int r = vi >> 4, c4 = vi & 15;
    int ci = idxl[r];
    float4 qv = *(const float4*)&codebook[(size_t)ci * 64 + c4 * 4];
    *(float4*)&q_out[(size_t)s * NCD + r * 64 + c4 * 4] = qv;
  }
}

// ---------------------------------------------------------------------------
extern "C" void kernel_launch(void* const* d_in, const int* in_sizes, int n_in,
                              void* d_out, int out_size, void* d_ws, size_t ws_size,
                              hipStream_t stream) {
  (void)in_sizes; (void)n_in; (void)out_size; (void)ws_size;
  const float* x        = (const float*)d_in[0];
  const float* codebook = (const float*)d_in[1];
  const float* enc_w    = (const float*)d_in[2];
  const float* enc_b    = (const float*)d_in[3];
  const float* dec_w    = (const float*)d_in[4];
  const float* dec_b    = (const float*)d_in[5];

  float* out = (float*)d_out;
  float* r_out   = out;                       // [512][4096]
  float* q_out   = out + 2097152;             // [512][32][64]
  float* e_out   = out + 2097152 + 1048576;   // [512][32][64]
  float* idx_out = out + 2097152 + 2097152;   // [512][32] as float

  // ws layout (64 MB, phase-disjoint):
  //  phase 1: enc_w blobs [0,48M), k1 partials [48M,64M)
  //  phase 2: cost [0,64M)
  //  phase 3: q blob [0,2M), dec_w blob [2M,18M)
  char* ws = (char*)d_ws;
  u16* B1 = (u16*)ws;
  u16* B2 = (u16*)(ws + (16u << 20));
  u16* B3 = (u16*)(ws + (32u << 20));
  float* part = (float*)(ws + (48u << 20));
  float* cost_ws = (float*)ws;
  u16* qb  = (u16*)ws;
  u16* dwb = (u16*)(ws + (2u << 20));

  conv_split3<HID><<<4096, 256, 0, stream>>>(enc_w, B1, B2, B3);
  k1_gemm<<<dim3(4, 16, 4), 512, 0, stream>>>(x, B1, B2, B3, part);
  k_reduce_bias<<<1024, 256, 0, stream>>>(part, enc_b, e_out);
  k_cost<<<dim3(16384 / 64, CB / 256), 256, 0, stream>>>(e_out, codebook, cost_ws);
  k_assign<<<BATCH, 64, 0, stream>>>(cost_ws, codebook, q_out, idx_out);
  conv_split1<NCD><<<4096, 256, 0, stream>>>(dec_w, dwb);
  conv_split1<NCD><<<512, 256, 0, stream>>>(q_out, qb);
  k3_gemm<<<dim3(8, 32), 512, 0, stream>>>(qb, dwb, dec_b, r_out);
}

// Round 8
// 221.042 us; speedup vs baseline: 3.3076x; 1.0506x over previous
//
#include <hip/hip_runtime.h>
#include <hip/hip_bf16.h>
#include <stdint.h>

// Sizes
#define BATCH 512
#define HID   4096
#define NC    32
#define CD    64
#define CB    1024
#define NCD   2048   // NC*CD

typedef unsigned short u16;
typedef unsigned int   u32;
typedef __attribute__((ext_vector_type(8))) short short8;  // 8 bf16
typedef __attribute__((ext_vector_type(4))) float f32x4;

#define WAVE_SYNC()  asm volatile("s_waitcnt lgkmcnt(0)" ::: "memory")
#define SCHED_FENCE() __builtin_amdgcn_sched_barrier(0)

__device__ inline u16 bf16_rne(float f) {
  u32 u = __builtin_bit_cast(u32, f);
  u32 r = u + 0x7FFFu + ((u >> 16) & 1u);
  return (u16)(r >> 16);
}
__device__ inline float bf16_f32(u16 h) {
  u32 u = ((u32)h) << 16;
  return __builtin_bit_cast(float, u);
}
__device__ inline void split3(float a, u16& h1, u16& h2, u16& h3) {
  h1 = bf16_rne(a);
  float r1 = a - bf16_f32(h1);
  h2 = bf16_rne(r1);
  float r2 = r1 - bf16_f32(h2);
  h3 = bf16_rne(r2);
}
__device__ inline f32x4 mfma16(short8 a, short8 b, f32x4 c) {
  return __builtin_amdgcn_mfma_f32_16x16x32_bf16(a, b, c, 0, 0, 0);
}
__device__ inline void gload_lds16(const u16* g, u16* l) {
  __builtin_amdgcn_global_load_lds(
      (const __attribute__((address_space(1))) u32*)(const void*)g,
      (__attribute__((address_space(3))) u32*)(void*)l, 16, 0, 0);
}

union H8 { u16 h[8]; short8 v; };

// ---------------------------------------------------------------------------
// conv_split3: f32 [ROWS][K] -> 3 bf16 fragment-blob arrays.
// Coalesced read (128B segments) -> LDS f32 stage -> frag-layout split+store.
// ---------------------------------------------------------------------------
template<int K>
__global__ __launch_bounds__(256) void conv_split3(
    const float* __restrict__ src, u16* __restrict__ d1,
    u16* __restrict__ d2, u16* __restrict__ d3) {
  __shared__ float st[4][16][36];
  const int t = threadIdx.x;
  const int wv = t >> 6, l = t & 63;
  const int g = blockIdx.x * 4 + wv;
  const int rowbase = (g / (K / 32)) * 16;
  const int kbase   = (g % (K / 32)) * 32;
  {
    const float* s = src + (size_t)(rowbase + (l >> 2)) * K + kbase + (l & 3) * 8;
    *(f32x4*)&st[wv][l >> 2][(l & 3) * 8]     = *(const f32x4*)s;
    *(f32x4*)&st[wv][l >> 2][(l & 3) * 8 + 4] = *(const f32x4*)(s + 4);
  }
  __syncthreads();
  float vv[8];
  *(f32x4*)&vv[0] = *(const f32x4*)&st[wv][l & 15][(l >> 4) * 8];
  *(f32x4*)&vv[4] = *(const f32x4*)&st[wv][l & 15][(l >> 4) * 8 + 4];
  H8 o1, o2, o3;
#pragma unroll
  for (int i = 0; i < 8; ++i) split3(vv[i], o1.h[i], o2.h[i], o3.h[i]);
  size_t off = (size_t)g * 512 + l * 8;
  *(short8*)(d1 + off) = o1.v;
  *(short8*)(d2 + off) = o2.v;
  *(short8*)(d3 + off) = o3.v;
}

template<int K>
__global__ __launch_bounds__(256) void conv_split1(
    const float* __restrict__ src, u16* __restrict__ d1) {
  __shared__ float st[4][16][36];
  const int t = threadIdx.x;
  const int wv = t >> 6, l = t & 63;
  const int g = blockIdx.x * 4 + wv;
  const int rowbase = (g / (K / 32)) * 16;
  const int kbase   = (g % (K / 32)) * 32;
  {
    const float* s = src + (size_t)(rowbase + (l >> 2)) * K + kbase + (l & 3) * 8;
    *(f32x4*)&st[wv][l >> 2][(l & 3) * 8]     = *(const f32x4*)s;
    *(f32x4*)&st[wv][l >> 2][(l & 3) * 8 + 4] = *(const f32x4*)(s + 4);
  }
  __syncthreads();
  float vv[8];
  *(f32x4*)&vv[0] = *(const f32x4*)&st[wv][l & 15][(l >> 4) * 8];
  *(f32x4*)&vv[4] = *(const f32x4*)&st[wv][l & 15][(l >> 4) * 8 + 4];
  H8 o1;
#pragma unroll
  for (int i = 0; i < 8; ++i) o1.h[i] = bf16_rne(vv[i]);
  *(short8*)(d1 + (size_t)g * 512 + l * 8) = o1.v;
}

// ---------------------------------------------------------------------------
// k1_gemm: bf16x3 6-term emulated-f32 GEMM, 128x128 tile, split-K=4.
// Double-buffered LDS, As XOR-swizzle, XCD-aware tile remap: the 4 blocks
// sharing a B panel (same bn,kz) get the same dispatch-id%8 -> same XCD L2.
// ---------------------------------------------------------------------------
__global__ __launch_bounds__(512) void k1_gemm(
    const float* __restrict__ A,
    const u16* __restrict__ B1, const u16* __restrict__ B2,
    const u16* __restrict__ B3, float* __restrict__ part) {
  __shared__ u16 As[2][3][8][64][8];   // [buf][split][rowfrag][slot][8]
  __shared__ u16 Bs[2][3][8][64][8];   // [buf][split][colfrag][lane][8]
  const int t = threadIdx.x;
  const int wid = t >> 6, lane = t & 63;
  const int wrow = wid >> 2, wcol = wid & 3;
  // XCD-aware remap of (bm,bn,kz): d%8 = XCD (round-robin dispatch);
  // panel (bn,kz) constant within a d%8 class group of 4 consecutive slots.
  const int d = blockIdx.x + (blockIdx.y << 2) + (blockIdx.z << 6);
  const int xcd = d & 7, sl = d >> 3;            // sl 0..31
  const int panel = (xcd << 3) + (sl >> 2);      // 0..63
  const int bm = (sl & 3) * 128;
  const int bn = (panel & 15) * 128;
  const int kz = panel >> 4;
  const int kbase = kz * 1024;
  const int arow = t >> 2;
  const int akc  = t & 3;
  const float* aptr = A + (size_t)(bm + arow) * HID + kbase + akc * 8;
  const int arf = arow >> 4;
  const int p_w = (akc << 4) | (arow & 15);
  const int s_w = p_w ^ ((p_w >> 4) & 3);    // swizzled write slot
  const int s_r = lane ^ ((lane >> 4) & 3);  // swizzled read slot (same map)
  const size_t nf0 = (size_t)((bn >> 4) + wid);

  f32x4 acc[4][2];
#pragma unroll
  for (int r = 0; r < 4; ++r)
#pragma unroll
    for (int c = 0; c < 2; ++c) acc[r][c] = (f32x4)0.f;

  // prologue: stage ks=0 into buf 0
  {
    float va[8];
    *(f32x4*)&va[0] = *(const f32x4*)(aptr);
    *(f32x4*)&va[4] = *(const f32x4*)(aptr + 4);
    size_t gb = (nf0 * 128 + (size_t)(kbase >> 5)) * 512 + lane * 8;
    gload_lds16(B1 + gb, &Bs[0][0][wid][0][0]);
    gload_lds16(B2 + gb, &Bs[0][1][wid][0][0]);
    gload_lds16(B3 + gb, &Bs[0][2][wid][0][0]);
    H8 s1, s2, s3;
#pragma unroll
    for (int i = 0; i < 8; ++i) split3(va[i], s1.h[i], s2.h[i], s3.h[i]);
    *(short8*)&As[0][0][arf][s_w][0] = s1.v;
    *(short8*)&As[0][1][arf][s_w][0] = s2.v;
    *(short8*)&As[0][2][arf][s_w][0] = s3.v;
  }
  __syncthreads();

  for (int ks = 0; ks < 32; ++ks) {
    const int cur = ks & 1, nxt = cur ^ 1;
    float vb[8];
    if (ks < 31) {
      *(f32x4*)&vb[0] = *(const f32x4*)(aptr + (ks + 1) * 32);
      *(f32x4*)&vb[4] = *(const f32x4*)(aptr + (ks + 1) * 32 + 4);
      size_t gb = (nf0 * 128 + (size_t)((kbase >> 5) + ks + 1)) * 512 + lane * 8;
      gload_lds16(B1 + gb, &Bs[nxt][0][wid][0][0]);
      gload_lds16(B2 + gb, &Bs[nxt][1][wid][0][0]);
      gload_lds16(B3 + gb, &Bs[nxt][2][wid][0][0]);
    }
    short8 a0[4], a1[4], a2[4], b0[2], b1[2], b2[2];
#pragma unroll
    for (int r = 0; r < 4; ++r) {
      a0[r] = *(const short8*)&As[cur][0][wrow * 4 + r][s_r][0];
      a1[r] = *(const short8*)&As[cur][1][wrow * 4 + r][s_r][0];
      a2[r] = *(const short8*)&As[cur][2][wrow * 4 + r][s_r][0];
    }
#pragma unroll
    for (int c = 0; c < 2; ++c) {
      b0[c] = *(const short8*)&Bs[cur][0][wcol * 2 + c][lane][0];
      b1[c] = *(const short8*)&Bs[cur][1][wcol * 2 + c][lane][0];
      b2[c] = *(const short8*)&Bs[cur][2][wcol * 2 + c][lane][0];
    }
#pragma unroll
    for (int r = 0; r < 4; ++r)
#pragma unroll
      for (int c = 0; c < 2; ++c) {
        f32x4 dd = acc[r][c];
        dd = mfma16(a0[r], b0[c], dd);
        dd = mfma16(a0[r], b1[c], dd);
        dd = mfma16(a1[r], b0[c], dd);
        dd = mfma16(a1[r], b1[c], dd);
        dd = mfma16(a0[r], b2[c], dd);
        dd = mfma16(a2[r], b0[c], dd);
        acc[r][c] = dd;
      }
    if (ks < 31) {
      H8 s1, s2, s3;
#pragma unroll
      for (int i = 0; i < 8; ++i) split3(vb[i], s1.h[i], s2.h[i], s3.h[i]);
      *(short8*)&As[nxt][0][arf][s_w][0] = s1.v;
      *(short8*)&As[nxt][1][arf][s_w][0] = s2.v;
      *(short8*)&As[nxt][2][arf][s_w][0] = s3.v;
    }
    __syncthreads();
  }
  float* P = part + (size_t)kz * BATCH * NCD;
#pragma unroll
  for (int r = 0; r < 4; ++r)
#pragma unroll
    for (int c = 0; c < 2; ++c) {
      int row = bm + wrow * 64 + r * 16 + (lane >> 4) * 4;
      int col = bn + wcol * 32 + c * 16 + (lane & 15);
#pragma unroll
      for (int i = 0; i < 4; ++i)
        P[(size_t)(row + i) * NCD + col] = acc[r][c][i];
    }
}

// ---------------------------------------------------------------------------
__global__ __launch_bounds__(256) void k_reduce_bias(
    const float* __restrict__ part, const float* __restrict__ bias,
    float* __restrict__ e) {
  size_t o = ((size_t)blockIdx.x * 256 + threadIdx.x) * 4;
  int n = (int)(o & (NCD - 1));
  f32x4 s = *(const f32x4*)(part + o);
  s += *(const f32x4*)(part + (size_t)1 * BATCH * NCD + o);
  s += *(const f32x4*)(part + (size_t)2 * BATCH * NCD + o);
  s += *(const f32x4*)(part + (size_t)3 * BATCH * NCD + o);
  s += *(const f32x4*)(bias + n);
  *(f32x4*)(e + o) = s;
}

// ---------------------------------------------------------------------------
// k3_gemm: r = q @ dec_w.T + dec_b, plain bf16. XCD-aware remap: the 8 blocks
// sharing a dec_w panel (same bn) land on one XCD.
// ---------------------------------------------------------------------------
__global__ __launch_bounds__(512) void k3_gemm(
    const u16* __restrict__ Ab, const u16* __restrict__ Bb,
    const float* __restrict__ bias, float* __restrict__ C) {
  __shared__ u16 As[4][64][8];
  __shared__ u16 Bs[8][64][8];
  const int t = threadIdx.x;
  const int wid = t >> 6, lane = t & 63;
  const int wrow = wid >> 2, wcol = wid & 3;
  const int d = blockIdx.x + (blockIdx.y << 3);
  const int xcd = d & 7, sl = d >> 3;            // sl 0..31
  const int bn = ((xcd << 2) + (sl >> 3)) * 128; // 32 panels, 4 per XCD
  const int bm = (sl & 7) * 64;
  f32x4 acc[2][2];
#pragma unroll
  for (int r = 0; r < 2; ++r)
#pragma unroll
    for (int c = 0; c < 2; ++c) acc[r][c] = (f32x4)0.f;

  for (int ks = 0; ks < 64; ++ks) {
    {
      size_t gb = (((size_t)(bn >> 4) + wid) * 64 + ks) * 512 + lane * 8;
      gload_lds16(Bb + gb, &Bs[wid][0][0]);
      if (wid < 4) {
        size_t ga = (((size_t)(bm >> 4) + wid) * 64 + ks) * 512 + lane * 8;
        gload_lds16(Ab + ga, &As[wid][0][0]);
      }
    }
    __syncthreads();
    short8 a[2], b[2];
#pragma unroll
    for (int r = 0; r < 2; ++r) a[r] = *(const short8*)&As[wrow * 2 + r][lane][0];
#pragma unroll
    for (int c = 0; c < 2; ++c) b[c] = *(const short8*)&Bs[wcol * 2 + c][lane][0];
#pragma unroll
    for (int r = 0; r < 2; ++r)
#pragma unroll
      for (int c = 0; c < 2; ++c) acc[r][c] = mfma16(a[r], b[c], acc[r][c]);
    __syncthreads();
  }
#pragma unroll
  for (int r = 0; r < 2; ++r)
#pragma unroll
    for (int c = 0; c < 2; ++c) {
      int row = bm + wrow * 32 + r * 16 + (lane >> 4) * 4;
      int col = bn + wcol * 32 + c * 16 + (lane & 15);
      float bb = bias[col];
#pragma unroll
      for (int i = 0; i < 4; ++i)
        C[(size_t)(row + i) * HID + col] = acc[r][c][i] + bb;
    }
}

// ---------------------------------------------------------------------------
// k_cost (MFMA): cost[r][c] = sqrt(max(|e_r|^2 + |c_c|^2 - 2*e_r.c_c, 0)),
// dot via bf16x3 6-term MFMA over K=64 (error ~2^-25 rel ~= f32 noise).
// 128x128 tile, 8 waves; e/cb split in-kernel to LDS frag blobs.
// ---------------------------------------------------------------------------
__global__ __launch_bounds__(512) void k_cost(
    const float* __restrict__ e_glob,     // [16384][64]
    const float* __restrict__ codebook,   // [1024][64]
    float* __restrict__ cost) {           // [16384][1024]
  __shared__ u16 Ea[2][3][8][64][8];   // [kstep][split][rowfrag][lane][8]
  __shared__ u16 Cbs[2][3][8][64][8];  // [kstep][split][colfrag][lane][8]
  __shared__ float enorm[128], cnorm[128];
  const int t = threadIdx.x;
  const int wid = t >> 6, lane = t & 63;
  const int wrow = wid >> 2, wcol = wid & 3;
  const int r0 = blockIdx.x * 128;
  const int c0 = blockIdx.y * 128;

  // stage: each thread fills frag slot [*][*][wid][lane] for both ksteps
  {
    const int fr = lane & 15, kc = lane >> 4;
    const float* ea = e_glob   + (size_t)(r0 + wid * 16 + fr) * CD + kc * 8;
    const float* cb = codebook + (size_t)(c0 + wid * 16 + fr) * CD + kc * 8;
#pragma unroll
    for (int ks = 0; ks < 2; ++ks) {
      float va[8], vb[8];
      *(f32x4*)&va[0] = *(const f32x4*)(ea + ks * 32);
      *(f32x4*)&va[4] = *(const f32x4*)(ea + ks * 32 + 4);
      *(f32x4*)&vb[0] = *(const f32x4*)(cb + ks * 32);
      *(f32x4*)&vb[4] = *(const f32x4*)(cb + ks * 32 + 4);
      H8 a1, a2, a3, b1, b2, b3;
#pragma unroll
      for (int i = 0; i < 8; ++i) {
        split3(va[i], a1.h[i], a2.h[i], a3.h[i]);
        split3(vb[i], b1.h[i], b2.h[i], b3.h[i]);
      }
      *(short8*)&Ea[ks][0][wid][lane][0] = a1.v;
      *(short8*)&Ea[ks][1][wid][lane][0] = a2.v;
      *(short8*)&Ea[ks][2][wid][lane][0] = a3.v;
      *(short8*)&Cbs[ks][0][wid][lane][0] = b1.v;
      *(short8*)&Cbs[ks][1][wid][lane][0] = b2.v;
      *(short8*)&Cbs[ks][2][wid][lane][0] = b3.v;
    }
  }
  // norms (f32)
  if (t < 256) {
    const int which = t >> 7, idx = t & 127;
    const float* p = which ? codebook + (size_t)(c0 + idx) * CD
                           : e_glob   + (size_t)(r0 + idx) * CD;
    float s = 0.f;
#pragma unroll
    for (int k = 0; k < 16; ++k) {
      f32x4 v = *(const f32x4*)(p + k * 4);
      s += v.x * v.x + v.y * v.y + v.z * v.z + v.w * v.w;
    }
    if (which) cnorm[idx] = s; else enorm[idx] = s;
  }
  __syncthreads();

  f32x4 acc[4][2];
#pragma unroll
  for (int r = 0; r < 4; ++r)
#pragma unroll
    for (int c = 0; c < 2; ++c) acc[r][c] = (f32x4)0.f;
#pragma unroll
  for (int ks = 0; ks < 2; ++ks) {
    short8 a0[4], a1[4], a2[4], b0[2], b1[2], b2[2];
#pragma unroll
    for (int r = 0; r < 4; ++r) {
      a0[r] = *(const short8*)&Ea[ks][0][wrow * 4 + r][lane][0];
      a1[r] = *(const short8*)&Ea[ks][1][wrow * 4 + r][lane][0];
      a2[r] = *(const short8*)&Ea[ks][2][wrow * 4 + r][lane][0];
    }
#pragma unroll
    for (int c = 0; c < 2; ++c) {
      b0[c] = *(const short8*)&Cbs[ks][0][wcol * 2 + c][lane][0];
      b1[c] = *(const short8*)&Cbs[ks][1][wcol * 2 + c][lane][0];
      b2[c] = *(const short8*)&Cbs[ks][2][wcol * 2 + c][lane][0];
    }
#pragma unroll
    for (int r = 0; r < 4; ++r)
#pragma unroll
      for (int c = 0; c < 2; ++c) {
        f32x4 dd = acc[r][c];
        dd = mfma16(a0[r], b0[c], dd);
        dd = mfma16(a0[r], b1[c], dd);
        dd = mfma16(a1[r], b0[c], dd);
        dd = mfma16(a1[r], b1[c], dd);
        dd = mfma16(a0[r], b2[c], dd);
        dd = mfma16(a2[r], b0[c], dd);
        acc[r][c] = dd;
      }
  }
#pragma unroll
  for (int r = 0; r < 4; ++r)
#pragma unroll
    for (int c = 0; c < 2; ++c) {
      const int rl = wrow * 64 + r * 16 + (lane >> 4) * 4;
      const int cl = wcol * 32 + c * 16 + (lane & 15);
      const float cn = cnorm[cl];
#pragma unroll
      for (int i = 0; i < 4; ++i) {
        float d2 = enorm[rl + i] + cn - 2.f * acc[r][c][i];
        cost[(size_t)(r0 + rl + i) * CB + c0 + cl] = sqrtf(fmaxf(d2, 0.f));
      }
    }
}

// ---------------------------------------------------------------------------
// k_assign: one wave per sample. JV with ALL state in registers (unchanged).
// ---------------------------------------------------------------------------
__global__ __launch_bounds__(64, 1) void k_assign(
    const float* __restrict__ cost_g, const float* __restrict__ codebook,
    float* __restrict__ q_out, float* __restrict__ idx_out) {
  __shared__ int idxl[32];
  const int lane = threadIdx.x;
  const int s = blockIdx.x;
  const float* __restrict__ cost = cost_g + (size_t)s * NC * CB;

  double v_[16], minv_[16];
  u32 wp_[16];                        // low16 = way, high16 = pm
  double u_val = 0.0;                 // lane l holds u[l] (rows 1..32)
#pragma unroll
  for (int r = 0; r < 16; ++r) { v_[r] = 0.0; wp_[r] = 0; }

  float pf[16];                       // prefetched row for next phase
#pragma unroll
  for (int r = 0; r < 16; ++r) pf[r] = cost[r * 64 + lane];   // row 0 (phase 1)

  for (int i = 1; i <= NC; ++i) {
#pragma unroll
    for (int r = 0; r < 16; ++r) minv_[r] = 1e300;
    u32 col_used = 0;
    unsigned long long rowmask = 0ull;
    int j0 = 0;
    int i0 = i;
    int first = 1;
    for (int guard = 0; guard < 1056; ++guard) {
      rowmask |= (1ull << i0);
      const double ui0 = __shfl(u_val, i0);
      float cc[16];
      if (first) {
#pragma unroll
        for (int r = 0; r < 16; ++r) cc[r] = pf[r];
        if (i < NC) {                 // prefetch next phase's row i (0-based)
#pragma unroll
          for (int r = 0; r < 16; ++r)
            pf[r] = cost[(size_t)i * CB + r * 64 + lane];
        }
        first = 0;
      } else {
        const float* crow = cost + (size_t)(i0 - 1) * CB;
#pragma unroll
        for (int r = 0; r < 16; ++r) cc[r] = crow[r * 64 + lane];
      }
      double bv = 1e301; int bj = 1 << 20;
#pragma unroll
      for (int r = 0; r < 16; ++r) {
        const int j = 1 + lane + r * 64;
        if (!((col_used >> r) & 1u)) {
          double cur = (double)cc[r] - ui0 - v_[r];
          if (cur < minv_[r]) { minv_[r] = cur; wp_[r] = (wp_[r] & 0xFFFF0000u) | (u32)j0; }
          if (minv_[r] < bv) { bv = minv_[r]; bj = j; }
        }
      }
#pragma unroll
      for (int off = 1; off < 64; off <<= 1) {
        double ov = __shfl_xor(bv, off);
        int oj = __shfl_xor(bj, off);
        if (ov < bv || (ov == bv && oj < bj)) { bv = ov; bj = oj; }
      }
      const double delta = bv;
      const int k = bj;
      if ((rowmask >> lane) & 1ull) u_val += delta;
#pragma unroll
      for (int r = 0; r < 16; ++r) {
        const int j = 1 + lane + r * 64;
        if ((col_used >> r) & 1u) v_[r] -= delta;
        else {
          minv_[r] -= delta;
          if (j == k) col_used |= (1u << r);
        }
      }
      const int rk = (k - 1) >> 6, kl = (k - 1) & 63;
      u32 sel = 0;
#pragma unroll
      for (int r = 0; r < 16; ++r) if (r == rk) sel = wp_[r];
      const int pmk = ((u32)__shfl((int)sel, kl)) >> 16;
      j0 = k;
      if (pmk == 0) break;
      i0 = pmk;
    }
    int jj = j0;
    while (jj != 0) {
      const int rj = (jj - 1) >> 6, lj = (jj - 1) & 63;
      u32 wsel = 0;
#pragma unroll
      for (int r = 0; r < 16; ++r) if (r == rj) wsel = wp_[r];
      const int j1 = ((u32)__shfl((int)wsel, lj)) & 0xFFFFu;
      int newpm;
      if (j1 == 0) newpm = i;
      else {
        const int r1 = (j1 - 1) >> 6, l1 = (j1 - 1) & 63;
        u32 psel = 0;
#pragma unroll
        for (int r = 0; r < 16; ++r) if (r == r1) psel = wp_[r];
        newpm = ((u32)__shfl((int)psel, l1)) >> 16;
      }
#pragma unroll
      for (int r = 0; r < 16; ++r)
        if (lane == lj && r == rj) wp_[r] = (wp_[r] & 0xFFFFu) | ((u32)newpm << 16);
      jj = j1;
    }
  }

#pragma unroll
  for (int r = 0; r < 16; ++r) {
    const u32 pm = wp_[r] >> 16;
    if (pm > 0) idxl[pm - 1] = lane + r * 64;
  }
  WAVE_SYNC(); SCHED_FENCE();
  if (lane < NC) idx_out[(size_t)s * NC + lane] = (float)idxl[lane];
#pragma unroll
  for (int p = 0; p < 8; ++p) {
    int vi = p * 64 + lane;
    int r = vi >> 4, c4 = vi & 15;
    int ci = idxl[r];
    float4 qv = *(const float4*)&codebook[(size_t)ci * 64 + c4 * 4];
    *(float4*)&q_out[(size_t)s * NCD + r * 64 + c4 * 4] = qv;
  }
}

// ---------------------------------------------------------------------------
extern "C" void kernel_launch(void* const* d_in, const int* in_sizes, int n_in,
                              void* d_out, int out_size, void* d_ws, size_t ws_size,
                              hipStream_t stream) {
  (void)in_sizes; (void)n_in; (void)out_size; (void)ws_size;
  const float* x        = (const float*)d_in[0];
  const float* codebook = (const float*)d_in[1];
  const float* enc_w    = (const float*)d_in[2];
  const float* enc_b    = (const float*)d_in[3];
  const float* dec_w    = (const float*)d_in[4];
  const float* dec_b    = (const float*)d_in[5];

  float* out = (float*)d_out;
  float* r_out   = out;                       // [512][4096]
  float* q_out   = out + 2097152;             // [512][32][64]
  float* e_out   = out + 2097152 + 1048576;   // [512][32][64]
  float* idx_out = out + 2097152 + 2097152;   // [512][32] as float

  // ws layout (64 MB, phase-disjoint):
  //  phase 1: enc_w blobs [0,48M), k1 partials [48M,64M)
  //  phase 2: cost [0,64M)
  //  phase 3: q blob [0,2M), dec_w blob [2M,18M)
  char* ws = (char*)d_ws;
  u16* B1 = (u16*)ws;
  u16* B2 = (u16*)(ws + (16u << 20));
  u16* B3 = (u16*)(ws + (32u << 20));
  float* part = (float*)(ws + (48u << 20));
  float* cost_ws = (float*)ws;
  u16* qb  = (u16*)ws;
  u16* dwb = (u16*)(ws + (2u << 20));

  conv_split3<HID><<<4096, 256, 0, stream>>>(enc_w, B1, B2, B3);
  k1_gemm<<<dim3(4, 16, 4), 512, 0, stream>>>(x, B1, B2, B3, part);
  k_reduce_bias<<<1024, 256, 0, stream>>>(part, enc_b, e_out);
  k_cost<<<dim3(128, 8), 512, 0, stream>>>(e_out, codebook, cost_ws);
  k_assign<<<BATCH, 64, 0, stream>>>(cost_ws, codebook, q_out, idx_out);
  conv_split1<NCD><<<4096, 256, 0, stream>>>(dec_w, dwb);
  conv_split1<NCD><<<512, 256, 0, stream>>>(q_out, qb);
  k3_gemm<<<dim3(8, 32), 512, 0, stream>>>(qb, dwb, dec_b, r_out);
}

// Round 10
// 220.978 us; speedup vs baseline: 3.3085x; 1.0003x over previous
//
#include <hip/hip_runtime.h>
#include <hip/hip_bf16.h>
#include <stdint.h>

// Sizes
#define BATCH 512
#define HID   4096
#define NC    32
#define CD    64
#define CB    1024
#define NCD   2048   // NC*CD

typedef unsigned short u16;
typedef unsigned int   u32;
typedef __attribute__((ext_vector_type(8))) short short8;  // 8 bf16
typedef __attribute__((ext_vector_type(4))) float f32x4;

#define WAVE_SYNC()  asm volatile("s_waitcnt lgkmcnt(0)" ::: "memory")
#define SCHED_FENCE() __builtin_amdgcn_sched_barrier(0)

__device__ inline u16 bf16_rne(float f) {
  u32 u = __builtin_bit_cast(u32, f);
  u32 r = u + 0x7FFFu + ((u >> 16) & 1u);
  return (u16)(r >> 16);
}
__device__ inline float bf16_f32(u16 h) {
  u32 u = ((u32)h) << 16;
  return __builtin_bit_cast(float, u);
}
__device__ inline void split3(float a, u16& h1, u16& h2, u16& h3) {
  h1 = bf16_rne(a);
  float r1 = a - bf16_f32(h1);
  h2 = bf16_rne(r1);
  float r2 = r1 - bf16_f32(h2);
  h3 = bf16_rne(r2);
}
__device__ inline f32x4 mfma16(short8 a, short8 b, f32x4 c) {
  return __builtin_amdgcn_mfma_f32_16x16x32_bf16(a, b, c, 0, 0, 0);
}
__device__ inline void gload_lds16(const u16* g, u16* l) {
  __builtin_amdgcn_global_load_lds(
      (const __attribute__((address_space(1))) u32*)(const void*)g,
      (__attribute__((address_space(3))) u32*)(void*)l, 16, 0, 0);
}

union H8 { u16 h[8]; short8 v; };

// ---------------------------------------------------------------------------
// conv_split3: f32 [ROWS][K] -> 3 bf16 fragment-blob arrays (coalesced read).
// ---------------------------------------------------------------------------
template<int K>
__global__ __launch_bounds__(256) void conv_split3(
    const float* __restrict__ src, u16* __restrict__ d1,
    u16* __restrict__ d2, u16* __restrict__ d3) {
  __shared__ float st[4][16][36];
  const int t = threadIdx.x;
  const int wv = t >> 6, l = t & 63;
  const int g = blockIdx.x * 4 + wv;
  const int rowbase = (g / (K / 32)) * 16;
  const int kbase   = (g % (K / 32)) * 32;
  {
    const float* s = src + (size_t)(rowbase + (l >> 2)) * K + kbase + (l & 3) * 8;
    *(f32x4*)&st[wv][l >> 2][(l & 3) * 8]     = *(const f32x4*)s;
    *(f32x4*)&st[wv][l >> 2][(l & 3) * 8 + 4] = *(const f32x4*)(s + 4);
  }
  __syncthreads();
  float vv[8];
  *(f32x4*)&vv[0] = *(const f32x4*)&st[wv][l & 15][(l >> 4) * 8];
  *(f32x4*)&vv[4] = *(const f32x4*)&st[wv][l & 15][(l >> 4) * 8 + 4];
  H8 o1, o2, o3;
#pragma unroll
  for (int i = 0; i < 8; ++i) split3(vv[i], o1.h[i], o2.h[i], o3.h[i]);
  size_t off = (size_t)g * 512 + l * 8;
  *(short8*)(d1 + off) = o1.v;
  *(short8*)(d2 + off) = o2.v;
  *(short8*)(d3 + off) = o3.v;
}

template<int K>
__global__ __launch_bounds__(256) void conv_split1(
    const float* __restrict__ src, u16* __restrict__ d1) {
  __shared__ float st[4][16][36];
  const int t = threadIdx.x;
  const int wv = t >> 6, l = t & 63;
  const int g = blockIdx.x * 4 + wv;
  const int rowbase = (g / (K / 32)) * 16;
  const int kbase   = (g % (K / 32)) * 32;
  {
    const float* s = src + (size_t)(rowbase + (l >> 2)) * K + kbase + (l & 3) * 8;
    *(f32x4*)&st[wv][l >> 2][(l & 3) * 8]     = *(const f32x4*)s;
    *(f32x4*)&st[wv][l >> 2][(l & 3) * 8 + 4] = *(const f32x4*)(s + 4);
  }
  __syncthreads();
  float vv[8];
  *(f32x4*)&vv[0] = *(const f32x4*)&st[wv][l & 15][(l >> 4) * 8];
  *(f32x4*)&vv[4] = *(const f32x4*)&st[wv][l & 15][(l >> 4) * 8 + 4];
  H8 o1;
#pragma unroll
  for (int i = 0; i < 8; ++i) o1.h[i] = bf16_rne(vv[i]);
  *(short8*)(d1 + (size_t)g * 512 + l * 8) = o1.v;
}

// ---------------------------------------------------------------------------
// k1_gemm: bf16x3 6-term emulated-f32 GEMM (error ~2^-26 rel — the validated
// minimum precision: 5-term's 2^-18 flips Hungarian assignments, round 9).
// 128x128 tile, split-K=4, dbuf LDS, As XOR-swizzle, XCD-aware remap.
// ---------------------------------------------------------------------------
__global__ __launch_bounds__(512) void k1_gemm(
    const float* __restrict__ A,
    const u16* __restrict__ B1, const u16* __restrict__ B2,
    const u16* __restrict__ B3, float* __restrict__ part) {
  __shared__ u16 As[2][3][8][64][8];   // [buf][split][rowfrag][slot][8]
  __shared__ u16 Bs[2][3][8][64][8];   // [buf][split][colfrag][lane][8]
  const int t = threadIdx.x;
  const int wid = t >> 6, lane = t & 63;
  const int wrow = wid >> 2, wcol = wid & 3;
  const int d = blockIdx.x + (blockIdx.y << 2) + (blockIdx.z << 6);
  const int xcd = d & 7, sl = d >> 3;            // sl 0..31
  const int panel = (xcd << 3) + (sl >> 2);      // 0..63
  const int bm = (sl & 3) * 128;
  const int bn = (panel & 15) * 128;
  const int kz = panel >> 4;
  const int kbase = kz * 1024;
  const int arow = t >> 2;
  const int akc  = t & 3;
  const float* aptr = A + (size_t)(bm + arow) * HID + kbase + akc * 8;
  const int arf = arow >> 4;
  const int p_w = (akc << 4) | (arow & 15);
  const int s_w = p_w ^ ((p_w >> 4) & 3);    // swizzled write slot
  const int s_r = lane ^ ((lane >> 4) & 3);  // swizzled read slot (same map)
  const size_t nf0 = (size_t)((bn >> 4) + wid);

  f32x4 acc[4][2];
#pragma unroll
  for (int r = 0; r < 4; ++r)
#pragma unroll
    for (int c = 0; c < 2; ++c) acc[r][c] = (f32x4)0.f;

  // prologue: stage ks=0 into buf 0
  {
    float va[8];
    *(f32x4*)&va[0] = *(const f32x4*)(aptr);
    *(f32x4*)&va[4] = *(const f32x4*)(aptr + 4);
    size_t gb = (nf0 * 128 + (size_t)(kbase >> 5)) * 512 + lane * 8;
    gload_lds16(B1 + gb, &Bs[0][0][wid][0][0]);
    gload_lds16(B2 + gb, &Bs[0][1][wid][0][0]);
    gload_lds16(B3 + gb, &Bs[0][2][wid][0][0]);
    H8 s1, s2, s3;
#pragma unroll
    for (int i = 0; i < 8; ++i) split3(va[i], s1.h[i], s2.h[i], s3.h[i]);
    *(short8*)&As[0][0][arf][s_w][0] = s1.v;
    *(short8*)&As[0][1][arf][s_w][0] = s2.v;
    *(short8*)&As[0][2][arf][s_w][0] = s3.v;
  }
  __syncthreads();

  for (int ks = 0; ks < 32; ++ks) {
    const int cur = ks & 1, nxt = cur ^ 1;
    float vb[8];
    if (ks < 31) {
      *(f32x4*)&vb[0] = *(const f32x4*)(aptr + (ks + 1) * 32);
      *(f32x4*)&vb[4] = *(const f32x4*)(aptr + (ks + 1) * 32 + 4);
      size_t gb = (nf0 * 128 + (size_t)((kbase >> 5) + ks + 1)) * 512 + lane * 8;
      gload_lds16(B1 + gb, &Bs[nxt][0][wid][0][0]);
      gload_lds16(B2 + gb, &Bs[nxt][1][wid][0][0]);
      gload_lds16(B3 + gb, &Bs[nxt][2][wid][0][0]);
    }
    short8 a0[4], a1[4], a2[4], b0[2], b1[2], b2[2];
#pragma unroll
    for (int r = 0; r < 4; ++r) {
      a0[r] = *(const short8*)&As[cur][0][wrow * 4 + r][s_r][0];
      a1[r] = *(const short8*)&As[cur][1][wrow * 4 + r][s_r][0];
      a2[r] = *(const short8*)&As[cur][2][wrow * 4 + r][s_r][0];
    }
#pragma unroll
    for (int c = 0; c < 2; ++c) {
      b0[c] = *(const short8*)&Bs[cur][0][wcol * 2 + c][lane][0];
      b1[c] = *(const short8*)&Bs[cur][1][wcol * 2 + c][lane][0];
      b2[c] = *(const short8*)&Bs[cur][2][wcol * 2 + c][lane][0];
    }
#pragma unroll
    for (int r = 0; r < 4; ++r)
#pragma unroll
      for (int c = 0; c < 2; ++c) {
        f32x4 dd = acc[r][c];
        dd = mfma16(a0[r], b0[c], dd);
        dd = mfma16(a0[r], b1[c], dd);
        dd = mfma16(a1[r], b0[c], dd);
        dd = mfma16(a1[r], b1[c], dd);
        dd = mfma16(a0[r], b2[c], dd);
        dd = mfma16(a2[r], b0[c], dd);
        acc[r][c] = dd;
      }
    if (ks < 31) {
      H8 s1, s2, s3;
#pragma unroll
      for (int i = 0; i < 8; ++i) split3(vb[i], s1.h[i], s2.h[i], s3.h[i]);
      *(short8*)&As[nxt][0][arf][s_w][0] = s1.v;
      *(short8*)&As[nxt][1][arf][s_w][0] = s2.v;
      *(short8*)&As[nxt][2][arf][s_w][0] = s3.v;
    }
    __syncthreads();
  }
  float* P = part + (size_t)kz * BATCH * NCD;
#pragma unroll
  for (int r = 0; r < 4; ++r)
#pragma unroll
    for (int c = 0; c < 2; ++c) {
      int row = bm + wrow * 64 + r * 16 + (lane >> 4) * 4;
      int col = bn + wcol * 32 + c * 16 + (lane & 15);
#pragma unroll
      for (int i = 0; i < 4; ++i)
        P[(size_t)(row + i) * NCD + col] = acc[r][c][i];
    }
}

// ---------------------------------------------------------------------------
__global__ __launch_bounds__(256) void k_reduce_bias(
    const float* __restrict__ part, const float* __restrict__ bias,
    float* __restrict__ e) {
  size_t o = ((size_t)blockIdx.x * 256 + threadIdx.x) * 4;
  int n = (int)(o & (NCD - 1));
  f32x4 s = *(const f32x4*)(part + o);
  s += *(const f32x4*)(part + (size_t)1 * BATCH * NCD + o);
  s += *(const f32x4*)(part + (size_t)2 * BATCH * NCD + o);
  s += *(const f32x4*)(part + (size_t)3 * BATCH * NCD + o);
  s += *(const f32x4*)(bias + n);
  *(f32x4*)(e + o) = s;
}

// ---------------------------------------------------------------------------
// k3_gemm: r = q @ dec_w.T + dec_b, plain bf16, XCD-aware remap.
// ---------------------------------------------------------------------------
__global__ __launch_bounds__(512) void k3_gemm(
    const u16* __restrict__ Ab, const u16* __restrict__ Bb,
    const float* __restrict__ bias, float* __restrict__ C) {
  __shared__ u16 As[4][64][8];
  __shared__ u16 Bs[8][64][8];
  const int t = threadIdx.x;
  const int wid = t >> 6, lane = t & 63;
  const int wrow = wid >> 2, wcol = wid & 3;
  const int d = blockIdx.x + (blockIdx.y << 3);
  const int xcd = d & 7, sl = d >> 3;            // sl 0..31
  const int bn = ((xcd << 2) + (sl >> 3)) * 128; // 32 panels, 4 per XCD
  const int bm = (sl & 7) * 64;
  f32x4 acc[2][2];
#pragma unroll
  for (int r = 0; r < 2; ++r)
#pragma unroll
    for (int c = 0; c < 2; ++c) acc[r][c] = (f32x4)0.f;

  for (int ks = 0; ks < 64; ++ks) {
    {
      size_t gb = (((size_t)(bn >> 4) + wid) * 64 + ks) * 512 + lane * 8;
      gload_lds16(Bb + gb, &Bs[wid][0][0]);
      if (wid < 4) {
        size_t ga = (((size_t)(bm >> 4) + wid) * 64 + ks) * 512 + lane * 8;
        gload_lds16(Ab + ga, &As[wid][0][0]);
      }
    }
    __syncthreads();
    short8 a[2], b[2];
#pragma unroll
    for (int r = 0; r < 2; ++r) a[r] = *(const short8*)&As[wrow * 2 + r][lane][0];
#pragma unroll
    for (int c = 0; c < 2; ++c) b[c] = *(const short8*)&Bs[wcol * 2 + c][lane][0];
#pragma unroll
    for (int r = 0; r < 2; ++r)
#pragma unroll
      for (int c = 0; c < 2; ++c) acc[r][c] = mfma16(a[r], b[c], acc[r][c]);
    __syncthreads();
  }
#pragma unroll
  for (int r = 0; r < 2; ++r)
#pragma unroll
    for (int c = 0; c < 2; ++c) {
      int row = bm + wrow * 32 + r * 16 + (lane >> 4) * 4;
      int col = bn + wcol * 32 + c * 16 + (lane & 15);
      float bb = bias[col];
#pragma unroll
      for (int i = 0; i < 4; ++i)
        C[(size_t)(row + i) * HID + col] = acc[r][c][i] + bb;
    }
}

// ---------------------------------------------------------------------------
// k_cost (MFMA): 6-term bf16x3 over K=64 (unchanged from round 8).
// ---------------------------------------------------------------------------
__global__ __launch_bounds__(512) void k_cost(
    const float* __restrict__ e_glob,     // [16384][64]
    const float* __restrict__ codebook,   // [1024][64]
    float* __restrict__ cost) {           // [16384][1024]
  __shared__ u16 Ea[2][3][8][64][8];   // [kstep][split][rowfrag][lane][8]
  __shared__ u16 Cbs[2][3][8][64][8];  // [kstep][split][colfrag][lane][8]
  __shared__ float enorm[128], cnorm[128];
  const int t = threadIdx.x;
  const int wid = t >> 6, lane = t & 63;
  const int wrow = wid >> 2, wcol = wid & 3;
  const int r0 = blockIdx.x * 128;
  const int c0 = blockIdx.y * 128;

  {
    const int fr = lane & 15, kc = lane >> 4;
    const float* ea = e_glob   + (size_t)(r0 + wid * 16 + fr) * CD + kc * 8;
    const float* cb = codebook + (size_t)(c0 + wid * 16 + fr) * CD + kc * 8;
#pragma unroll
    for (int ks = 0; ks < 2; ++ks) {
      float va[8], vb[8];
      *(f32x4*)&va[0] = *(const f32x4*)(ea + ks * 32);
      *(f32x4*)&va[4] = *(const f32x4*)(ea + ks * 32 + 4);
      *(f32x4*)&vb[0] = *(const f32x4*)(cb + ks * 32);
      *(f32x4*)&vb[4] = *(const f32x4*)(cb + ks * 32 + 4);
      H8 a1, a2, a3, b1, b2, b3;
#pragma unroll
      for (int i = 0; i < 8; ++i) {
        split3(va[i], a1.h[i], a2.h[i], a3.h[i]);
        split3(vb[i], b1.h[i], b2.h[i], b3.h[i]);
      }
      *(short8*)&Ea[ks][0][wid][lane][0] = a1.v;
      *(short8*)&Ea[ks][1][wid][lane][0] = a2.v;
      *(short8*)&Ea[ks][2][wid][lane][0] = a3.v;
      *(short8*)&Cbs[ks][0][wid][lane][0] = b1.v;
      *(short8*)&Cbs[ks][1][wid][lane][0] = b2.v;
      *(short8*)&Cbs[ks][2][wid][lane][0] = b3.v;
    }
  }
  if (t < 256) {
    const int which = t >> 7, idx = t & 127;
    const float* p = which ? codebook + (size_t)(c0 + idx) * CD
                           : e_glob   + (size_t)(r0 + idx) * CD;
    float s = 0.f;
#pragma unroll
    for (int k = 0; k < 16; ++k) {
      f32x4 v = *(const f32x4*)(p + k * 4);
      s += v.x * v.x + v.y * v.y + v.z * v.z + v.w * v.w;
    }
    if (which) cnorm[idx] = s; else enorm[idx] = s;
  }
  __syncthreads();

  f32x4 acc[4][2];
#pragma unroll
  for (int r = 0; r < 4; ++r)
#pragma unroll
    for (int c = 0; c < 2; ++c) acc[r][c] = (f32x4)0.f;
#pragma unroll
  for (int ks = 0; ks < 2; ++ks) {
    short8 a0[4], a1[4], a2[4], b0[2], b1[2], b2[2];
#pragma unroll
    for (int r = 0; r < 4; ++r) {
      a0[r] = *(const short8*)&Ea[ks][0][wrow * 4 + r][lane][0];
      a1[r] = *(const short8*)&Ea[ks][1][wrow * 4 + r][lane][0];
      a2[r] = *(const short8*)&Ea[ks][2][wrow * 4 + r][lane][0];
    }
#pragma unroll
    for (int c = 0; c < 2; ++c) {
      b0[c] = *(const short8*)&Cbs[ks][0][wcol * 2 + c][lane][0];
      b1[c] = *(const short8*)&Cbs[ks][1][wcol * 2 + c][lane][0];
      b2[c] = *(const short8*)&Cbs[ks][2][wcol * 2 + c][lane][0];
    }
#pragma unroll
    for (int r = 0; r < 4; ++r)
#pragma unroll
      for (int c = 0; c < 2; ++c) {
        f32x4 dd = acc[r][c];
        dd = mfma16(a0[r], b0[c], dd);
        dd = mfma16(a0[r], b1[c], dd);
        dd = mfma16(a1[r], b0[c], dd);
        dd = mfma16(a1[r], b1[c], dd);
        dd = mfma16(a0[r], b2[c], dd);
        dd = mfma16(a2[r], b0[c], dd);
        acc[r][c] = dd;
      }
  }
#pragma unroll
  for (int r = 0; r < 4; ++r)
#pragma unroll
    for (int c = 0; c < 2; ++c) {
      const int rl = wrow * 64 + r * 16 + (lane >> 4) * 4;
      const int cl = wcol * 32 + c * 16 + (lane & 15);
      const float cn = cnorm[cl];
#pragma unroll
      for (int i = 0; i < 4; ++i) {
        float d2 = enorm[rl + i] + cn - 2.f * acc[r][c][i];
        cost[(size_t)(r0 + rl + i) * CB + c0 + cl] = sqrtf(fmaxf(d2, 0.f));
      }
    }
}

// ---------------------------------------------------------------------------
// k_assign: one wave per sample, all-register JV. pm[k] extracted right
// after the argmin butterfly; next row's loads issued BEFORE dual updates
// (L2 latency overlaps update VALU work). Arithmetic identical to r5-r8.
// ---------------------------------------------------------------------------
__global__ __launch_bounds__(64, 1) void k_assign(
    const float* __restrict__ cost_g, const float* __restrict__ codebook,
    float* __restrict__ q_out, float* __restrict__ idx_out) {
  __shared__ int idxl[32];
  const int lane = threadIdx.x;
  const int s = blockIdx.x;
  const float* __restrict__ cost = cost_g + (size_t)s * NC * CB;

  double v_[16], minv_[16];
  u32 wp_[16];                        // low16 = way, high16 = pm
  double u_val = 0.0;                 // lane l holds u[l] (rows 1..32)
#pragma unroll
  for (int r = 0; r < 16; ++r) { v_[r] = 0.0; wp_[r] = 0; }

  float pf[16];                       // prefetched first row of next phase
#pragma unroll
  for (int r = 0; r < 16; ++r) pf[r] = cost[r * 64 + lane];   // row 0

  for (int i = 1; i <= NC; ++i) {
#pragma unroll
    for (int r = 0; r < 16; ++r) minv_[r] = 1e300;
    u32 col_used = 0;
    unsigned long long rowmask = 0ull;
    int j0 = 0;
    int i0 = i;
    float cc[16];
#pragma unroll
    for (int r = 0; r < 16; ++r) cc[r] = pf[r];
    int first = 1;
    for (int guard = 0; guard < 1056; ++guard) {
      rowmask |= (1ull << i0);
      const double ui0 = __shfl(u_val, i0);
      if (first && i < NC) {          // prefetch next phase's first row
#pragma unroll
        for (int r = 0; r < 16; ++r)
          pf[r] = cost[(size_t)i * CB + r * 64 + lane];
      }
      first = 0;
      double bv = 1e301; int bj = 1 << 20;
#pragma unroll
      for (int r = 0; r < 16; ++r) {
        const int j = 1 + lane + r * 64;
        if (!((col_used >> r) & 1u)) {
          double cur = (double)cc[r] - ui0 - v_[r];
          if (cur < minv_[r]) { minv_[r] = cur; wp_[r] = (wp_[r] & 0xFFFF0000u) | (u32)j0; }
          if (minv_[r] < bv) { bv = minv_[r]; bj = j; }
        }
      }
#pragma unroll
      for (int off = 1; off < 64; off <<= 1) {
        double ov = __shfl_xor(bv, off);
        int oj = __shfl_xor(bj, off);
        if (ov < bv || (ov == bv && oj < bj)) { bv = ov; bj = oj; }
      }
      const double delta = bv;
      const int k = bj;
      // extract pm[k] FIRST, then issue next row's loads (overlaps updates)
      const int rk = (k - 1) >> 6, kl = (k - 1) & 63;
      u32 sel = 0;
#pragma unroll
      for (int r = 0; r < 16; ++r) if (r == rk) sel = wp_[r];
      const int pmk = ((u32)__shfl((int)sel, kl)) >> 16;
      float ccn[16];
      if (pmk > 0) {
        const float* crow = cost + (size_t)(pmk - 1) * CB;
#pragma unroll
        for (int r = 0; r < 16; ++r) ccn[r] = crow[r * 64 + lane];
      }
      // dual updates (u via row-mask, v/minv per-lane)
      if ((rowmask >> lane) & 1ull) u_val += delta;
#pragma unroll
      for (int r = 0; r < 16; ++r) {
        const int j = 1 + lane + r * 64;
        if ((col_used >> r) & 1u) v_[r] -= delta;
        else {
          minv_[r] -= delta;
          if (j == k) col_used |= (1u << r);
        }
      }
      j0 = k;
      if (pmk == 0) break;
      i0 = pmk;
#pragma unroll
      for (int r = 0; r < 16; ++r) cc[r] = ccn[r];
    }
    // augment along the path (register wp, wave-uniform walk)
    int jj = j0;
    while (jj != 0) {
      const int rj = (jj - 1) >> 6, lj = (jj - 1) & 63;
      u32 wsel = 0;
#pragma unroll
      for (int r = 0; r < 16; ++r) if (r == rj) wsel = wp_[r];
      const int j1 = ((u32)__shfl((int)wsel, lj)) & 0xFFFFu;
      int newpm;
      if (j1 == 0) newpm = i;
      else {
        const int r1 = (j1 - 1) >> 6, l1 = (j1 - 1) & 63;
        u32 psel = 0;
#pragma unroll
        for (int r = 0; r < 16; ++r) if (r == r1) psel = wp_[r];
        newpm = ((u32)__shfl((int)psel, l1)) >> 16;
      }
#pragma unroll
      for (int r = 0; r < 16; ++r)
        if (lane == lj && r == rj) wp_[r] = (wp_[r] & 0xFFFFu) | ((u32)newpm << 16);
      jj = j1;
    }
  }

#pragma unroll
  for (int r = 0; r < 16; ++r) {
    const u32 pm = wp_[r] >> 16;
    if (pm > 0) idxl[pm - 1] = lane + r * 64;
  }
  WAVE_SYNC(); SCHED_FENCE();
  if (lane < NC) idx_out[(size_t)s * NC + lane] = (float)idxl[lane];
#pragma unroll
  for (int p = 0; p < 8; ++p) {
    int vi = p * 64 + lane;
    int r = vi >> 4, c4 = vi & 15;
    int ci = idxl[r];
    float4 qv = *(const float4*)&codebook[(size_t)ci * 64 + c4 * 4];
    *(float4*)&q_out[(size_t)s * NCD + r * 64 + c4 * 4] = qv;
  }
}

// ---------------------------------------------------------------------------
extern "C" void kernel_launch(void* const* d_in, const int* in_sizes, int n_in,
                              void* d_out, int out_size, void* d_ws, size_t ws_size,
                              hipStream_t stream) {
  (void)in_sizes; (void)n_in; (void)out_size; (void)ws_size;
  const float* x        = (const float*)d_in[0];
  const float* codebook = (const float*)d_in[1];
  const float* enc_w    = (const float*)d_in[2];
  const float* enc_b    = (const float*)d_in[3];
  const float* dec_w    = (const float*)d_in[4];
  const float* dec_b    = (const float*)d_in[5];

  float* out = (float*)d_out;
  float* r_out   = out;                       // [512][4096]
  float* q_out   = out + 2097152;             // [512][32][64]
  float* e_out   = out + 2097152 + 1048576;   // [512][32][64]
  float* idx_out = out + 2097152 + 2097152;   // [512][32] as float

  // ws layout (64 MB, phase-disjoint):
  //  phase 1: enc_w blobs [0,48M), k1 partials [48M,64M)
  //  phase 2: cost [0,64M)
  //  phase 3: q blob [0,2M), dec_w blob [2M,18M)
  char* ws = (char*)d_ws;
  u16* B1 = (u16*)ws;
  u16* B2 = (u16*)(ws + (16u << 20));
  u16* B3 = (u16*)(ws + (32u << 20));
  float* part = (float*)(ws + (48u << 20));
  float* cost_ws = (float*)ws;
  u16* qb  = (u16*)ws;
  u16* dwb = (u16*)(ws + (2u << 20));

  conv_split3<HID><<<4096, 256, 0, stream>>>(enc_w, B1, B2, B3);
  k1_gemm<<<dim3(4, 16, 4), 512, 0, stream>>>(x, B1, B2, B3, part);
  k_reduce_bias<<<1024, 256, 0, stream>>>(part, enc_b, e_out);
  k_cost<<<dim3(128, 8), 512, 0, stream>>>(e_out, codebook, cost_ws);
  k_assign<<<BATCH, 64, 0, stream>>>(cost_ws, codebook, q_out, idx_out);
  conv_split1<NCD><<<4096, 256, 0, stream>>>(dec_w, dwb);
  conv_split1<NCD><<<512, 256, 0, stream>>>(q_out, qb);
  k3_gemm<<<dim3(8, 32), 512, 0, stream>>>(qb, dwb, dec_b, r_out);
}